// Round 4
// baseline (995.365 us; speedup 1.0000x reference)
//
#include <hip/hip_runtime.h>

#define GCN_N 100000
#define GCN_H 128
#define GCN_G 256
#define BKT_S 128                      // dst nodes per bucket
#define BKT_SHIFT 7

// ---------------- bf16 helpers ----------------

__device__ __forceinline__ unsigned short f2bf(float f) {
    unsigned u = __float_as_uint(f);
    unsigned r = u + 0x7FFFu + ((u >> 16) & 1u);   // round to nearest even
    return (unsigned short)(r >> 16);
}
__device__ __forceinline__ float bf2f(unsigned short h) {
    return __uint_as_float(((unsigned)h) << 16);
}

// ---------------- bucketed CSR build ----------------

__global__ __launch_bounds__(256) void bucket_count_kernel(const int* __restrict__ dst,
                                                           int* __restrict__ bcount, int E) {
    int e = blockIdx.x * 256 + threadIdx.x;
    if (e < E) atomicAdd(&bcount[dst[e] >> BKT_SHIFT], 1);
}

__global__ void bucket_scan_kernel(const int* __restrict__ bcount,
                                   int* __restrict__ bbase,
                                   int* __restrict__ rowptr, int K, int n) {
    if (threadIdx.x == 0 && blockIdx.x == 0) {
        int run = 0;
        for (int i = 0; i < K; i++) { bbase[i] = run; run += bcount[i]; }
        bbase[K] = run;
        rowptr[n] = run;
    }
}

__global__ __launch_bounds__(256) void bucket_fill_kernel(const int* __restrict__ src,
                                                          const int* __restrict__ dst,
                                                          const int* __restrict__ bbase,
                                                          int* __restrict__ bcursor,
                                                          int2* __restrict__ epair, int E) {
    int e = blockIdx.x * 256 + threadIdx.x;
    if (e < E) {
        int d = dst[e];
        int b = d >> BKT_SHIFT;
        int pos = bbase[b] + atomicAdd(&bcursor[b], 1);
        epair[pos] = make_int2(src[e], d);
    }
}

// one workgroup per bucket: local hist -> local scan -> rowptr/dis -> csrc
__global__ __launch_bounds__(256) void csr_build_kernel(const int2* __restrict__ epair,
                                                        const int* __restrict__ bbase,
                                                        int* __restrict__ rowptr,
                                                        float* __restrict__ dis,
                                                        int* __restrict__ csrc, int n) {
    __shared__ int lcount[BKT_S];
    __shared__ int lscan[BKT_S];
    __shared__ int wsums[2];
    int b = blockIdx.x;
    int tid = threadIdx.x;
    int lane = tid & 63, wid = tid >> 6;
    int nodebase = b << BKT_SHIFT;
    int ebeg = bbase[b], eend = bbase[b + 1];

    if (tid < BKT_S) lcount[tid] = 0;
    __syncthreads();
    for (int e = ebeg + tid; e < eend; e += 256)
        atomicAdd(&lcount[epair[e].y - nodebase], 1);
    __syncthreads();

    int v = (tid < BKT_S) ? lcount[tid] : 0;
    int iv = v;
    #pragma unroll
    for (int d = 1; d < 64; d <<= 1) {
        int x = __shfl_up(iv, d, 64);
        if (lane >= d) iv += x;
    }
    if (tid < BKT_S && lane == 63) wsums[wid] = iv;
    __syncthreads();
    if (tid == 0) { int t0 = wsums[0]; wsums[0] = 0; wsums[1] = t0; }
    __syncthreads();
    if (tid < BKT_S) {
        int ex = wsums[wid] + iv - v;            // exclusive local scan
        lscan[tid] = ex;                         // doubles as cursor
        int node = nodebase + tid;
        if (node < n) {
            rowptr[node] = ebeg + ex;
            dis[node] = rsqrtf((float)(v + 1));  // deg = indeg + self-loop
        }
    }
    __syncthreads();
    for (int e = ebeg + tid; e < eend; e += 256) {
        int2 p = epair[e];
        int pos = atomicAdd(&lscan[p.y - nodebase], 1);
        csrc[ebeg + pos] = p.x;
    }
}

// ---------------- layer 0: 5-dim scaled copy + aggregation ----------------

__global__ __launch_bounds__(256) void xscale_kernel(const float* __restrict__ x,
                                                     const float* __restrict__ dis,
                                                     float* __restrict__ xsp, int n) {
    int i = blockIdx.x * 256 + threadIdx.x;
    if (i >= n) return;
    float di = dis[i];
    float4 a;
    a.x = x[(size_t)i * 5 + 0] * di;
    a.y = x[(size_t)i * 5 + 1] * di;
    a.z = x[(size_t)i * 5 + 2] * di;
    a.w = x[(size_t)i * 5 + 3] * di;
    float a4 = x[(size_t)i * 5 + 4] * di;
    ((float4*)(xsp + (size_t)i * 8))[0] = a;
    xsp[(size_t)i * 8 + 4] = a4;
}

__global__ __launch_bounds__(256) void aggx_kernel(const float* __restrict__ xsp,
                                                   const float* __restrict__ dis,
                                                   const int* __restrict__ rowptr,
                                                   const int* __restrict__ csrc,
                                                   float* __restrict__ a0p, int n) {
    int i = blockIdx.x * 256 + threadIdx.x;
    if (i >= n) return;
    float4 acc = ((const float4*)(xsp + (size_t)i * 8))[0];
    float acc4 = xsp[(size_t)i * 8 + 4];
    int r0 = rowptr[i], r1 = rowptr[i + 1];
    for (int e = r0; e < r1; e++) {
        int s = csrc[e];
        float4 v = ((const float4*)(xsp + (size_t)s * 8))[0];
        acc.x += v.x; acc.y += v.y; acc.z += v.z; acc.w += v.w;
        acc4 += xsp[(size_t)s * 8 + 4];
    }
    float di = dis[i];
    acc.x *= di; acc.y *= di; acc.z *= di; acc.w *= di; acc4 *= di;
    ((float4*)(a0p + (size_t)i * 8))[0] = acc;
    a0p[(size_t)i * 8 + 4] = acc4;
}

// ------- fused mm: t1 = bf16( dis ⊙ (relu(a0@W0 + b0) @ W1) ) -------

__global__ __launch_bounds__(256) void mmfused_kernel(const float* __restrict__ a0p,
                                                      const float* __restrict__ W0,
                                                      const float* __restrict__ b0,
                                                      const float* __restrict__ W1,
                                                      const float* __restrict__ dis,
                                                      unsigned short* __restrict__ t1b, int n) {
    __shared__ __align__(16) float sW[128 * 128];   // 64 KB (W1)
    __shared__ __align__(16) float sH[32 * 128];    // 16 KB (relu'd h1 rows)
    int tid = threadIdx.x;
    int group = tid >> 5, lane = tid & 31;

    float4 w0r[5];
    #pragma unroll
    for (int j = 0; j < 5; j++) w0r[j] = ((const float4*)(W0 + j * 128))[lane];
    float4 b0r = ((const float4*)b0)[lane];

    const float4* W14 = (const float4*)W1;
    float4* sW4 = (float4*)sW;
    for (int i = tid; i < 128 * 32; i += 256) sW4[i] = W14[i];

    int rowBase = blockIdx.x * 32;
    int r0 = group * 4;
    #pragma unroll
    for (int rr = 0; rr < 4; rr++) {
        int row = rowBase + r0 + rr;
        const float* ar = a0p + (size_t)row * 8;
        float4 h = b0r;
        #pragma unroll
        for (int j = 0; j < 5; j++) {
            float aj = ar[j];
            h.x = fmaf(aj, w0r[j].x, h.x);
            h.y = fmaf(aj, w0r[j].y, h.y);
            h.z = fmaf(aj, w0r[j].z, h.z);
            h.w = fmaf(aj, w0r[j].w, h.w);
        }
        h.x = fmaxf(h.x, 0.f); h.y = fmaxf(h.y, 0.f);
        h.z = fmaxf(h.z, 0.f); h.w = fmaxf(h.w, 0.f);
        ((float4*)(sH + (r0 + rr) * 128))[lane] = h;
    }
    __syncthreads();

    float4 acc0 = make_float4(0.f,0.f,0.f,0.f);
    float4 acc1 = make_float4(0.f,0.f,0.f,0.f);
    float4 acc2 = make_float4(0.f,0.f,0.f,0.f);
    float4 acc3 = make_float4(0.f,0.f,0.f,0.f);
    const float* a0ptr = sH + (r0 + 0) * 128;
    const float* a1ptr = sH + (r0 + 1) * 128;
    const float* a2ptr = sH + (r0 + 2) * 128;
    const float* a3ptr = sH + (r0 + 3) * 128;
    #pragma unroll 8
    for (int k = 0; k < 128; k++) {
        float4 w = sW4[k * 32 + lane];
        float a0 = a0ptr[k], a1 = a1ptr[k], a2 = a2ptr[k], a3 = a3ptr[k];
        acc0.x = fmaf(a0, w.x, acc0.x); acc0.y = fmaf(a0, w.y, acc0.y);
        acc0.z = fmaf(a0, w.z, acc0.z); acc0.w = fmaf(a0, w.w, acc0.w);
        acc1.x = fmaf(a1, w.x, acc1.x); acc1.y = fmaf(a1, w.y, acc1.y);
        acc1.z = fmaf(a1, w.z, acc1.z); acc1.w = fmaf(a1, w.w, acc1.w);
        acc2.x = fmaf(a2, w.x, acc2.x); acc2.y = fmaf(a2, w.y, acc2.y);
        acc2.z = fmaf(a2, w.z, acc2.z); acc2.w = fmaf(a2, w.w, acc2.w);
        acc3.x = fmaf(a3, w.x, acc3.x); acc3.y = fmaf(a3, w.y, acc3.y);
        acc3.z = fmaf(a3, w.z, acc3.z); acc3.w = fmaf(a3, w.w, acc3.w);
    }
    float dd[4];
    dd[0] = dis[rowBase + r0 + 0]; dd[1] = dis[rowBase + r0 + 1];
    dd[2] = dis[rowBase + r0 + 2]; dd[3] = dis[rowBase + r0 + 3];
    float4 accs[4] = {acc0, acc1, acc2, acc3};
    #pragma unroll
    for (int rr = 0; rr < 4; rr++) {
        float4 a = accs[rr];
        float d = dd[rr];
        a.x *= d; a.y *= d; a.z *= d; a.w *= d;
        uint2 p;
        p.x = (unsigned)f2bf(a.x) | ((unsigned)f2bf(a.y) << 16);
        p.y = (unsigned)f2bf(a.z) | ((unsigned)f2bf(a.w) << 16);
        ((uint2*)(t1b + (size_t)(rowBase + r0 + rr) * GCN_H))[lane] = p;
    }
}

// ---------------- w2l = W2 @ lin_w, c2 = b2 . lin_w ----------------

__global__ __launch_bounds__(256) void w2l_kernel(const float* __restrict__ W2,
                                                  const float* __restrict__ b2,
                                                  const float* __restrict__ lw,
                                                  float* __restrict__ w2l,
                                                  float* __restrict__ c2) {
    __shared__ float slw[128];
    int tid = threadIdx.x;
    if (tid < 128) slw[tid] = lw[tid];
    __syncthreads();
    if (tid < 128) {
        float s = 0.f;
        #pragma unroll 8
        for (int j = 0; j < 128; j++) s = fmaf(W2[tid * 128 + j], slw[j], s);
        w2l[tid] = s;
    } else if (tid == 128) {
        float s = 0.f;
        for (int j = 0; j < 128; j++) s = fmaf(b2[j], slw[j], s);
        c2[0] = s;
    }
}

// --------- layer-1 aggregation (bf16 gather) fused with layer-2 dot ---------
// conv1[i] = dis[i]*(t1[i] + sum t1[src]) + b1 ;  z[i] = dis[i]*dot(relu(conv1), w2l)
__global__ __launch_bounds__(256) void agg1_kernel(const unsigned short* __restrict__ t1b,
                                                   const float* __restrict__ dis,
                                                   const int* __restrict__ rowptr,
                                                   const int* __restrict__ csrc,
                                                   const float* __restrict__ b1,
                                                   const float* __restrict__ w2l,
                                                   float* __restrict__ z, int n) {
    int group = threadIdx.x >> 5, lane = threadIdx.x & 31;
    int i = blockIdx.x * 8 + group;
    if (i >= n) return;
    const ushort4* t4 = (const ushort4*)t1b;     // 32 x ushort4 per row
    ushort4 sv = t4[(size_t)i * 32 + lane];
    float4 acc = make_float4(bf2f(sv.x), bf2f(sv.y), bf2f(sv.z), bf2f(sv.w));
    int r0 = rowptr[i], r1 = rowptr[i + 1];
    int e = r0;
    for (; e + 3 < r1; e += 4) {
        int s0 = csrc[e], s1 = csrc[e + 1], s2 = csrc[e + 2], s3 = csrc[e + 3];
        ushort4 v0 = t4[(size_t)s0 * 32 + lane];
        ushort4 v1 = t4[(size_t)s1 * 32 + lane];
        ushort4 v2 = t4[(size_t)s2 * 32 + lane];
        ushort4 v3 = t4[(size_t)s3 * 32 + lane];
        acc.x += (bf2f(v0.x) + bf2f(v1.x)) + (bf2f(v2.x) + bf2f(v3.x));
        acc.y += (bf2f(v0.y) + bf2f(v1.y)) + (bf2f(v2.y) + bf2f(v3.y));
        acc.z += (bf2f(v0.z) + bf2f(v1.z)) + (bf2f(v2.z) + bf2f(v3.z));
        acc.w += (bf2f(v0.w) + bf2f(v1.w)) + (bf2f(v2.w) + bf2f(v3.w));
    }
    for (; e < r1; e++) {
        ushort4 v = t4[(size_t)csrc[e] * 32 + lane];
        acc.x += bf2f(v.x); acc.y += bf2f(v.y);
        acc.z += bf2f(v.z); acc.w += bf2f(v.w);
    }
    float di = dis[i];
    float4 b4 = ((const float4*)b1)[lane];
    acc.x = fmaf(di, acc.x, b4.x);
    acc.y = fmaf(di, acc.y, b4.y);
    acc.z = fmaf(di, acc.z, b4.z);
    acc.w = fmaf(di, acc.w, b4.w);
    acc.x = fmaxf(acc.x, 0.f); acc.y = fmaxf(acc.y, 0.f);
    acc.z = fmaxf(acc.z, 0.f); acc.w = fmaxf(acc.w, 0.f);
    float4 w = ((const float4*)w2l)[lane];
    float d = acc.x * w.x + acc.y * w.y + acc.z * w.z + acc.w * w.w;
    #pragma unroll
    for (int o = 16; o > 0; o >>= 1) d += __shfl_down(d, o, 32);
    if (lane == 0) z[i] = di * d;
}

// ---------------- layer-2 scalar aggregation ----------------

__global__ __launch_bounds__(256) void aggz_kernel(const float* __restrict__ z,
                                                   const float* __restrict__ dis,
                                                   const int* __restrict__ rowptr,
                                                   const int* __restrict__ csrc,
                                                   float* __restrict__ nd, int n) {
    int i = blockIdx.x * 256 + threadIdx.x;
    if (i >= n) return;
    float acc = z[i];
    int r0 = rowptr[i], r1 = rowptr[i + 1];
    int e = r0;
    for (; e + 3 < r1; e += 4) {
        acc += (z[csrc[e]] + z[csrc[e + 1]]) + (z[csrc[e + 2]] + z[csrc[e + 3]]);
    }
    for (; e < r1; e++) acc += z[csrc[e]];
    nd[i] = dis[i] * acc;
}

// ---------------- pooling (segment reduce over sorted batch) ----------------

__global__ __launch_bounds__(256) void boundary_kernel(const int* __restrict__ batch,
                                                       int* __restrict__ gstart, int n) {
    int i = blockIdx.x * 256 + threadIdx.x;
    if (i >= n) return;
    int b = batch[i];
    int pb = (i == 0) ? -1 : batch[i - 1];
    for (int g = pb + 1; g <= b; g++) gstart[g] = i;
    if (i == n - 1) {
        for (int g = b + 1; g <= GCN_G; g++) gstart[g] = n;
    }
}

__global__ __launch_bounds__(256) void reduce_kernel(const float* __restrict__ nd,
                                                     const int* __restrict__ gstart,
                                                     const float* __restrict__ c2,
                                                     const float* __restrict__ lb,
                                                     float* __restrict__ out) {
    __shared__ float ssum[4];
    int g = blockIdx.x;
    int s = gstart[g], epos = gstart[g + 1];
    int tid = threadIdx.x, lane = tid & 63, wid = tid >> 6;
    float sum = 0.f;
    for (int i = s + tid; i < epos; i += 256) sum += nd[i];
    #pragma unroll
    for (int o = 32; o > 0; o >>= 1) sum += __shfl_down(sum, o, 64);
    if (lane == 0) ssum[wid] = sum;
    __syncthreads();
    if (tid == 0) {
        float tot = ssum[0] + ssum[1] + ssum[2] + ssum[3];
        float cnt = (float)max(epos - s, 1);
        float v = tot / cnt + c2[0] + lb[0];
        out[g] = 1.f / (1.f + expf(-v));
    }
}

// ---------------- launch ----------------

extern "C" void kernel_launch(void* const* d_in, const int* in_sizes, int n_in,
                              void* d_out, int out_size, void* d_ws, size_t ws_size,
                              hipStream_t stream) {
    const float* x   = (const float*)d_in[0];
    const int*   ei  = (const int*)d_in[1];
    const int*   bat = (const int*)d_in[2];
    const float* W0  = (const float*)d_in[3];
    const float* b0  = (const float*)d_in[4];
    const float* W1  = (const float*)d_in[5];
    const float* b1  = (const float*)d_in[6];
    const float* W2  = (const float*)d_in[7];
    const float* b2  = (const float*)d_in[8];
    const float* lw  = (const float*)d_in[9];
    const float* lb  = (const float*)d_in[10];
    float* out = (float*)d_out;

    const int N = GCN_N;
    const int E = in_sizes[1] / 2;
    const int K = (N + BKT_S - 1) >> BKT_SHIFT;

    char* ws = (char*)d_ws;
    size_t off = 0;
    auto alloc = [&](size_t bytes) {
        size_t o = off;
        off += (bytes + 255) & ~(size_t)255;
        return o;
    };
    int*   bcount  = (int*)(ws + alloc((size_t)K * 4));
    int*   bcursor = (int*)(ws + alloc((size_t)K * 4));
    int*   bbase   = (int*)(ws + alloc((size_t)(K + 1) * 4));
    int2*  epair   = (int2*)(ws + alloc((size_t)E * 8));
    int*   rowptr  = (int*)(ws + alloc((size_t)(N + 1) * 4));
    float* dis     = (float*)(ws + alloc((size_t)N * 4));
    int*   csrc    = (int*)(ws + alloc((size_t)E * 4));
    float* xsp     = (float*)(ws + alloc((size_t)N * 8 * 4));
    float* a0p     = (float*)(ws + alloc((size_t)N * 8 * 4));
    unsigned short* t1b = (unsigned short*)(ws + alloc((size_t)N * GCN_H * 2));
    float* z       = (float*)(ws + alloc((size_t)N * 4));
    float* nd      = (float*)(ws + alloc((size_t)N * 4));
    int*   gstart  = (int*)(ws + alloc((size_t)(GCN_G + 1) * 4));
    float* w2l     = (float*)(ws + alloc(128 * 4));
    float* c2      = (float*)(ws + alloc(4));

    const int* src = ei;
    const int* dst = ei + E;

    hipMemsetAsync(bcount, 0, (size_t)K * 4, stream);
    hipMemsetAsync(bcursor, 0, (size_t)K * 4, stream);

    bucket_count_kernel<<<(E + 255) / 256, 256, 0, stream>>>(dst, bcount, E);
    bucket_scan_kernel<<<1, 64, 0, stream>>>(bcount, bbase, rowptr, K, N);
    bucket_fill_kernel<<<(E + 255) / 256, 256, 0, stream>>>(src, dst, bbase, bcursor, epair, E);
    csr_build_kernel<<<K, 256, 0, stream>>>(epair, bbase, rowptr, dis, csrc, N);
    boundary_kernel<<<(N + 255) / 256, 256, 0, stream>>>(bat, gstart, N);
    w2l_kernel<<<1, 256, 0, stream>>>(W2, b2, lw, w2l, c2);

    xscale_kernel<<<(N + 255) / 256, 256, 0, stream>>>(x, dis, xsp, N);
    aggx_kernel<<<(N + 255) / 256, 256, 0, stream>>>(xsp, dis, rowptr, csrc, a0p, N);
    mmfused_kernel<<<N / 32, 256, 0, stream>>>(a0p, W0, b0, W1, dis, t1b, N);
    agg1_kernel<<<N / 8, 256, 0, stream>>>(t1b, dis, rowptr, csrc, b1, w2l, z, N);
    aggz_kernel<<<(N + 255) / 256, 256, 0, stream>>>(z, dis, rowptr, csrc, nd, N);

    reduce_kernel<<<GCN_G, 256, 0, stream>>>(nd, gstart, c2, lb, out);
}

// Round 5
// 223.729 us; speedup vs baseline: 4.4490x; 4.4490x over previous
//
#include <hip/hip_runtime.h>

#define GCN_N 100000
#define GCN_H 128
#define GCN_G 256
#define NPB_SHIFT 9                    // 512 nodes per bucket
#define NPB 512
#define NBKT 196                       // ceil(100000/512)
#define CHUNK 2048                     // edges per hist/partition block

// ---------------- bf16 helpers ----------------

__device__ __forceinline__ unsigned short f2bf(float f) {
    unsigned u = __float_as_uint(f);
    unsigned r = u + 0x7FFFu + ((u >> 16) & 1u);   // round to nearest even
    return (unsigned short)(r >> 16);
}
__device__ __forceinline__ float bf2f(unsigned short h) {
    return __uint_as_float(((unsigned)h) << 16);
}

// ---------------- CSR build: atomic-free radix partition ----------------

// pass A: per-block histogram over NBKT buckets
__global__ __launch_bounds__(256) void hist_kernel(const int* __restrict__ dst,
                                                   int* __restrict__ hist, int E) {
    __shared__ int lh[NBKT];
    int tid = threadIdx.x;
    if (tid < NBKT) lh[tid] = 0;
    __syncthreads();
    int e0 = blockIdx.x * CHUNK;
    #pragma unroll
    for (int i = 0; i < CHUNK / 256; i++) {
        int e = e0 + tid + i * 256;
        if (e < E) atomicAdd(&lh[dst[e] >> NPB_SHIFT], 1);
    }
    __syncthreads();
    if (tid < NBKT) hist[(size_t)blockIdx.x * NBKT + tid] = lh[tid];
}

// pass B1: per-bucket column scan over blocks -> offsT[k][b], btot[k]
__global__ __launch_bounds__(64) void scan_cols_kernel(const int* __restrict__ hist,
                                                       int* __restrict__ offsT,
                                                       int* __restrict__ btot, int B) {
    int k = blockIdx.x;
    int lane = threadIdx.x;
    int running = 0;
    for (int b0 = 0; b0 < B; b0 += 64) {
        int b = b0 + lane;
        int v = (b < B) ? hist[(size_t)b * NBKT + k] : 0;
        int iv = v;
        #pragma unroll
        for (int d = 1; d < 64; d <<= 1) {
            int x = __shfl_up(iv, d, 64);
            if (lane >= d) iv += x;
        }
        if (b < B) offsT[(size_t)k * B + b] = running + iv - v;   // exclusive
        running += __shfl(iv, 63, 64);
    }
    if (lane == 0) btot[k] = running;
}

// pass B2: serial scan of bucket totals (196 elements)
__global__ void bucket_base_kernel(const int* __restrict__ btot,
                                   int* __restrict__ bbase,
                                   int* __restrict__ rowptr, int n) {
    if (threadIdx.x == 0 && blockIdx.x == 0) {
        int run = 0;
        for (int i = 0; i < NBKT; i++) { bbase[i] = run; run += btot[i]; }
        bbase[NBKT] = run;
        rowptr[n] = run;
    }
}

// pass C: atomic-free (global) partition; LDS cursors seeded with exact offsets
__global__ __launch_bounds__(256) void partition_kernel(const int* __restrict__ src,
                                                        const int* __restrict__ dst,
                                                        const int* __restrict__ bbase,
                                                        const int* __restrict__ offsT,
                                                        int2* __restrict__ epair,
                                                        int E, int B) {
    __shared__ int cur[NBKT];
    int blk = blockIdx.x, tid = threadIdx.x;
    if (tid < NBKT) cur[tid] = bbase[tid] + offsT[(size_t)tid * B + blk];
    __syncthreads();
    int e0 = blk * CHUNK;
    #pragma unroll
    for (int i = 0; i < CHUNK / 256; i++) {
        int e = e0 + tid + i * 256;
        if (e < E) {
            int d = dst[e];
            int s = src[e];
            int pos = atomicAdd(&cur[d >> NPB_SHIFT], 1);
            epair[pos] = make_int2(s, d);
        }
    }
}

// pass D: one block per bucket: local hist -> scan -> rowptr/dis -> csrc
__global__ __launch_bounds__(512) void csr_build_kernel(const int2* __restrict__ epair,
                                                        const int* __restrict__ bbase,
                                                        int* __restrict__ rowptr,
                                                        float* __restrict__ dis,
                                                        int* __restrict__ csrc, int n) {
    __shared__ int lcount[NPB];
    __shared__ int lcur[NPB];
    __shared__ int wsums[8];
    int k = blockIdx.x, tid = threadIdx.x;
    int lane = tid & 63, wid = tid >> 6;
    int nodebase = k << NPB_SHIFT;
    int ebeg = bbase[k], eend = bbase[k + 1];

    lcount[tid] = 0;
    __syncthreads();
    for (int e = ebeg + tid; e < eend; e += 512)
        atomicAdd(&lcount[epair[e].y - nodebase], 1);
    __syncthreads();

    int v = lcount[tid];
    int iv = v;
    #pragma unroll
    for (int d = 1; d < 64; d <<= 1) {
        int x = __shfl_up(iv, d, 64);
        if (lane >= d) iv += x;
    }
    if (lane == 63) wsums[wid] = iv;
    __syncthreads();
    if (tid == 0) {
        int r = 0;
        #pragma unroll
        for (int w = 0; w < 8; w++) { int t = wsums[w]; wsums[w] = r; r += t; }
    }
    __syncthreads();
    int ex = wsums[wid] + iv - v;                // exclusive local scan
    lcur[tid] = ex;
    int node = nodebase + tid;
    if (node < n) {
        rowptr[node] = ebeg + ex;
        dis[node] = rsqrtf((float)(v + 1));      // deg = indeg + self-loop
    }
    __syncthreads();
    for (int e = ebeg + tid; e < eend; e += 512) {
        int2 p = epair[e];
        int pos = atomicAdd(&lcur[p.y - nodebase], 1);
        csrc[ebeg + pos] = p.x;
    }
}

// ---------------- layer 0: 5-dim scaled copy + aggregation ----------------

__global__ __launch_bounds__(256) void xscale_kernel(const float* __restrict__ x,
                                                     const float* __restrict__ dis,
                                                     float* __restrict__ xsp, int n) {
    int i = blockIdx.x * 256 + threadIdx.x;
    if (i >= n) return;
    float di = dis[i];
    float4 a;
    a.x = x[(size_t)i * 5 + 0] * di;
    a.y = x[(size_t)i * 5 + 1] * di;
    a.z = x[(size_t)i * 5 + 2] * di;
    a.w = x[(size_t)i * 5 + 3] * di;
    float a4 = x[(size_t)i * 5 + 4] * di;
    ((float4*)(xsp + (size_t)i * 8))[0] = a;
    xsp[(size_t)i * 8 + 4] = a4;
}

__global__ __launch_bounds__(256) void aggx_kernel(const float* __restrict__ xsp,
                                                   const float* __restrict__ dis,
                                                   const int* __restrict__ rowptr,
                                                   const int* __restrict__ csrc,
                                                   float* __restrict__ a0p, int n) {
    int i = blockIdx.x * 256 + threadIdx.x;
    if (i >= n) return;
    float4 acc = ((const float4*)(xsp + (size_t)i * 8))[0];
    float acc4 = xsp[(size_t)i * 8 + 4];
    int r0 = rowptr[i], r1 = rowptr[i + 1];
    for (int e = r0; e < r1; e++) {
        int s = csrc[e];
        float4 v = ((const float4*)(xsp + (size_t)s * 8))[0];
        acc.x += v.x; acc.y += v.y; acc.z += v.z; acc.w += v.w;
        acc4 += xsp[(size_t)s * 8 + 4];
    }
    float di = dis[i];
    acc.x *= di; acc.y *= di; acc.z *= di; acc.w *= di; acc4 *= di;
    ((float4*)(a0p + (size_t)i * 8))[0] = acc;
    a0p[(size_t)i * 8 + 4] = acc4;
}

// ------- fused mm: t1 = bf16( dis ⊙ (relu(a0@W0 + b0) @ W1) ) -------

__global__ __launch_bounds__(256) void mmfused_kernel(const float* __restrict__ a0p,
                                                      const float* __restrict__ W0,
                                                      const float* __restrict__ b0,
                                                      const float* __restrict__ W1,
                                                      const float* __restrict__ dis,
                                                      unsigned short* __restrict__ t1b, int n) {
    __shared__ __align__(16) float sW[128 * 128];   // 64 KB (W1)
    __shared__ __align__(16) float sH[32 * 128];    // 16 KB (relu'd h1 rows)
    int tid = threadIdx.x;
    int group = tid >> 5, lane = tid & 31;

    float4 w0r[5];
    #pragma unroll
    for (int j = 0; j < 5; j++) w0r[j] = ((const float4*)(W0 + j * 128))[lane];
    float4 b0r = ((const float4*)b0)[lane];

    const float4* W14 = (const float4*)W1;
    float4* sW4 = (float4*)sW;
    for (int i = tid; i < 128 * 32; i += 256) sW4[i] = W14[i];

    int rowBase = blockIdx.x * 32;
    int r0 = group * 4;
    #pragma unroll
    for (int rr = 0; rr < 4; rr++) {
        int row = rowBase + r0 + rr;
        const float* ar = a0p + (size_t)row * 8;
        float4 h = b0r;
        #pragma unroll
        for (int j = 0; j < 5; j++) {
            float aj = ar[j];
            h.x = fmaf(aj, w0r[j].x, h.x);
            h.y = fmaf(aj, w0r[j].y, h.y);
            h.z = fmaf(aj, w0r[j].z, h.z);
            h.w = fmaf(aj, w0r[j].w, h.w);
        }
        h.x = fmaxf(h.x, 0.f); h.y = fmaxf(h.y, 0.f);
        h.z = fmaxf(h.z, 0.f); h.w = fmaxf(h.w, 0.f);
        ((float4*)(sH + (r0 + rr) * 128))[lane] = h;
    }
    __syncthreads();

    float4 acc0 = make_float4(0.f,0.f,0.f,0.f);
    float4 acc1 = make_float4(0.f,0.f,0.f,0.f);
    float4 acc2 = make_float4(0.f,0.f,0.f,0.f);
    float4 acc3 = make_float4(0.f,0.f,0.f,0.f);
    const float* a0ptr = sH + (r0 + 0) * 128;
    const float* a1ptr = sH + (r0 + 1) * 128;
    const float* a2ptr = sH + (r0 + 2) * 128;
    const float* a3ptr = sH + (r0 + 3) * 128;
    #pragma unroll 8
    for (int k = 0; k < 128; k++) {
        float4 w = sW4[k * 32 + lane];
        float a0 = a0ptr[k], a1 = a1ptr[k], a2 = a2ptr[k], a3 = a3ptr[k];
        acc0.x = fmaf(a0, w.x, acc0.x); acc0.y = fmaf(a0, w.y, acc0.y);
        acc0.z = fmaf(a0, w.z, acc0.z); acc0.w = fmaf(a0, w.w, acc0.w);
        acc1.x = fmaf(a1, w.x, acc1.x); acc1.y = fmaf(a1, w.y, acc1.y);
        acc1.z = fmaf(a1, w.z, acc1.z); acc1.w = fmaf(a1, w.w, acc1.w);
        acc2.x = fmaf(a2, w.x, acc2.x); acc2.y = fmaf(a2, w.y, acc2.y);
        acc2.z = fmaf(a2, w.z, acc2.z); acc2.w = fmaf(a2, w.w, acc2.w);
        acc3.x = fmaf(a3, w.x, acc3.x); acc3.y = fmaf(a3, w.y, acc3.y);
        acc3.z = fmaf(a3, w.z, acc3.z); acc3.w = fmaf(a3, w.w, acc3.w);
    }
    float dd[4];
    dd[0] = dis[rowBase + r0 + 0]; dd[1] = dis[rowBase + r0 + 1];
    dd[2] = dis[rowBase + r0 + 2]; dd[3] = dis[rowBase + r0 + 3];
    float4 accs[4] = {acc0, acc1, acc2, acc3};
    #pragma unroll
    for (int rr = 0; rr < 4; rr++) {
        float4 a = accs[rr];
        float d = dd[rr];
        a.x *= d; a.y *= d; a.z *= d; a.w *= d;
        uint2 p;
        p.x = (unsigned)f2bf(a.x) | ((unsigned)f2bf(a.y) << 16);
        p.y = (unsigned)f2bf(a.z) | ((unsigned)f2bf(a.w) << 16);
        ((uint2*)(t1b + (size_t)(rowBase + r0 + rr) * GCN_H))[lane] = p;
    }
}

// ---------------- w2l = W2 @ lin_w, c2 = b2 . lin_w ----------------

__global__ __launch_bounds__(256) void w2l_kernel(const float* __restrict__ W2,
                                                  const float* __restrict__ b2,
                                                  const float* __restrict__ lw,
                                                  float* __restrict__ w2l,
                                                  float* __restrict__ c2) {
    __shared__ float slw[128];
    int tid = threadIdx.x;
    if (tid < 128) slw[tid] = lw[tid];
    __syncthreads();
    if (tid < 128) {
        float s = 0.f;
        #pragma unroll 8
        for (int j = 0; j < 128; j++) s = fmaf(W2[tid * 128 + j], slw[j], s);
        w2l[tid] = s;
    } else if (tid == 128) {
        float s = 0.f;
        for (int j = 0; j < 128; j++) s = fmaf(b2[j], slw[j], s);
        c2[0] = s;
    }
}

// --------- layer-1 aggregation (bf16 gather) fused with layer-2 dot ---------

__global__ __launch_bounds__(256) void agg1_kernel(const unsigned short* __restrict__ t1b,
                                                   const float* __restrict__ dis,
                                                   const int* __restrict__ rowptr,
                                                   const int* __restrict__ csrc,
                                                   const float* __restrict__ b1,
                                                   const float* __restrict__ w2l,
                                                   float* __restrict__ z, int n) {
    int group = threadIdx.x >> 5, lane = threadIdx.x & 31;
    int i = blockIdx.x * 8 + group;
    if (i >= n) return;
    const ushort4* t4 = (const ushort4*)t1b;     // 32 x ushort4 per row
    ushort4 sv = t4[(size_t)i * 32 + lane];
    float4 acc = make_float4(bf2f(sv.x), bf2f(sv.y), bf2f(sv.z), bf2f(sv.w));
    int r0 = rowptr[i], r1 = rowptr[i + 1];
    int e = r0;
    for (; e + 3 < r1; e += 4) {
        int s0 = csrc[e], s1 = csrc[e + 1], s2 = csrc[e + 2], s3 = csrc[e + 3];
        ushort4 v0 = t4[(size_t)s0 * 32 + lane];
        ushort4 v1 = t4[(size_t)s1 * 32 + lane];
        ushort4 v2 = t4[(size_t)s2 * 32 + lane];
        ushort4 v3 = t4[(size_t)s3 * 32 + lane];
        acc.x += (bf2f(v0.x) + bf2f(v1.x)) + (bf2f(v2.x) + bf2f(v3.x));
        acc.y += (bf2f(v0.y) + bf2f(v1.y)) + (bf2f(v2.y) + bf2f(v3.y));
        acc.z += (bf2f(v0.z) + bf2f(v1.z)) + (bf2f(v2.z) + bf2f(v3.z));
        acc.w += (bf2f(v0.w) + bf2f(v1.w)) + (bf2f(v2.w) + bf2f(v3.w));
    }
    for (; e < r1; e++) {
        ushort4 v = t4[(size_t)csrc[e] * 32 + lane];
        acc.x += bf2f(v.x); acc.y += bf2f(v.y);
        acc.z += bf2f(v.z); acc.w += bf2f(v.w);
    }
    float di = dis[i];
    float4 b4 = ((const float4*)b1)[lane];
    acc.x = fmaf(di, acc.x, b4.x);
    acc.y = fmaf(di, acc.y, b4.y);
    acc.z = fmaf(di, acc.z, b4.z);
    acc.w = fmaf(di, acc.w, b4.w);
    acc.x = fmaxf(acc.x, 0.f); acc.y = fmaxf(acc.y, 0.f);
    acc.z = fmaxf(acc.z, 0.f); acc.w = fmaxf(acc.w, 0.f);
    float4 w = ((const float4*)w2l)[lane];
    float d = acc.x * w.x + acc.y * w.y + acc.z * w.z + acc.w * w.w;
    #pragma unroll
    for (int o = 16; o > 0; o >>= 1) d += __shfl_down(d, o, 32);
    if (lane == 0) z[i] = di * d;
}

// ---------------- layer-2 scalar aggregation ----------------

__global__ __launch_bounds__(256) void aggz_kernel(const float* __restrict__ z,
                                                   const float* __restrict__ dis,
                                                   const int* __restrict__ rowptr,
                                                   const int* __restrict__ csrc,
                                                   float* __restrict__ nd, int n) {
    int i = blockIdx.x * 256 + threadIdx.x;
    if (i >= n) return;
    float acc = z[i];
    int r0 = rowptr[i], r1 = rowptr[i + 1];
    int e = r0;
    for (; e + 3 < r1; e += 4) {
        acc += (z[csrc[e]] + z[csrc[e + 1]]) + (z[csrc[e + 2]] + z[csrc[e + 3]]);
    }
    for (; e < r1; e++) acc += z[csrc[e]];
    nd[i] = dis[i] * acc;
}

// ---------------- pooling (segment reduce over sorted batch) ----------------

__global__ __launch_bounds__(256) void boundary_kernel(const int* __restrict__ batch,
                                                       int* __restrict__ gstart, int n) {
    int i = blockIdx.x * 256 + threadIdx.x;
    if (i >= n) return;
    int b = batch[i];
    int pb = (i == 0) ? -1 : batch[i - 1];
    for (int g = pb + 1; g <= b; g++) gstart[g] = i;
    if (i == n - 1) {
        for (int g = b + 1; g <= GCN_G; g++) gstart[g] = n;
    }
}

__global__ __launch_bounds__(256) void reduce_kernel(const float* __restrict__ nd,
                                                     const int* __restrict__ gstart,
                                                     const float* __restrict__ c2,
                                                     const float* __restrict__ lb,
                                                     float* __restrict__ out) {
    __shared__ float ssum[4];
    int g = blockIdx.x;
    int s = gstart[g], epos = gstart[g + 1];
    int tid = threadIdx.x, lane = tid & 63, wid = tid >> 6;
    float sum = 0.f;
    for (int i = s + tid; i < epos; i += 256) sum += nd[i];
    #pragma unroll
    for (int o = 32; o > 0; o >>= 1) sum += __shfl_down(sum, o, 64);
    if (lane == 0) ssum[wid] = sum;
    __syncthreads();
    if (tid == 0) {
        float tot = ssum[0] + ssum[1] + ssum[2] + ssum[3];
        float cnt = (float)max(epos - s, 1);
        float v = tot / cnt + c2[0] + lb[0];
        out[g] = 1.f / (1.f + expf(-v));
    }
}

// ---------------- launch ----------------

extern "C" void kernel_launch(void* const* d_in, const int* in_sizes, int n_in,
                              void* d_out, int out_size, void* d_ws, size_t ws_size,
                              hipStream_t stream) {
    const float* x   = (const float*)d_in[0];
    const int*   ei  = (const int*)d_in[1];
    const int*   bat = (const int*)d_in[2];
    const float* W0  = (const float*)d_in[3];
    const float* b0  = (const float*)d_in[4];
    const float* W1  = (const float*)d_in[5];
    const float* b1  = (const float*)d_in[6];
    const float* W2  = (const float*)d_in[7];
    const float* b2  = (const float*)d_in[8];
    const float* lw  = (const float*)d_in[9];
    const float* lb  = (const float*)d_in[10];
    float* out = (float*)d_out;

    const int N = GCN_N;
    const int E = in_sizes[1] / 2;
    const int B = (E + CHUNK - 1) / CHUNK;

    char* ws = (char*)d_ws;
    size_t off = 0;
    auto alloc = [&](size_t bytes) {
        size_t o = off;
        off += (bytes + 255) & ~(size_t)255;
        return o;
    };
    int*   hist    = (int*)(ws + alloc((size_t)B * NBKT * 4));
    int*   offsT   = (int*)(ws + alloc((size_t)NBKT * B * 4));
    int*   btot    = (int*)(ws + alloc((size_t)NBKT * 4));
    int*   bbase   = (int*)(ws + alloc((size_t)(NBKT + 1) * 4));
    int2*  epair   = (int2*)(ws + alloc((size_t)E * 8));
    int*   rowptr  = (int*)(ws + alloc((size_t)(N + 1) * 4));
    float* dis     = (float*)(ws + alloc((size_t)N * 4));
    int*   csrc    = (int*)(ws + alloc((size_t)E * 4));
    float* xsp     = (float*)(ws + alloc((size_t)N * 8 * 4));
    float* a0p     = (float*)(ws + alloc((size_t)N * 8 * 4));
    unsigned short* t1b = (unsigned short*)(ws + alloc((size_t)N * GCN_H * 2));
    float* z       = (float*)(ws + alloc((size_t)N * 4));
    float* nd      = (float*)(ws + alloc((size_t)N * 4));
    int*   gstart  = (int*)(ws + alloc((size_t)(GCN_G + 1) * 4));
    float* w2l     = (float*)(ws + alloc(128 * 4));
    float* c2      = (float*)(ws + alloc(4));

    const int* src = ei;
    const int* dst = ei + E;

    hist_kernel<<<B, 256, 0, stream>>>(dst, hist, E);
    scan_cols_kernel<<<NBKT, 64, 0, stream>>>(hist, offsT, btot, B);
    bucket_base_kernel<<<1, 64, 0, stream>>>(btot, bbase, rowptr, N);
    partition_kernel<<<B, 256, 0, stream>>>(src, dst, bbase, offsT, epair, E, B);
    csr_build_kernel<<<NBKT, 512, 0, stream>>>(epair, bbase, rowptr, dis, csrc, N);
    boundary_kernel<<<(N + 255) / 256, 256, 0, stream>>>(bat, gstart, N);
    w2l_kernel<<<1, 256, 0, stream>>>(W2, b2, lw, w2l, c2);

    xscale_kernel<<<(N + 255) / 256, 256, 0, stream>>>(x, dis, xsp, N);
    aggx_kernel<<<(N + 255) / 256, 256, 0, stream>>>(xsp, dis, rowptr, csrc, a0p, N);
    mmfused_kernel<<<N / 32, 256, 0, stream>>>(a0p, W0, b0, W1, dis, t1b, N);
    agg1_kernel<<<N / 8, 256, 0, stream>>>(t1b, dis, rowptr, csrc, b1, w2l, z, N);
    aggz_kernel<<<(N + 255) / 256, 256, 0, stream>>>(z, dis, rowptr, csrc, nd, N);

    reduce_kernel<<<GCN_G, 256, 0, stream>>>(nd, gstart, c2, lb, out);
}

// Round 6
// 189.881 us; speedup vs baseline: 5.2421x; 1.1783x over previous
//
#include <hip/hip_runtime.h>

#define GCN_N 100000
#define GCN_H 128
#define GCN_G 256
#define NPB_SHIFT 9                    // 512 nodes per bucket
#define NPB 512
#define NBKT 196                       // ceil(100000/512)
#define CHUNK 2048                     // edges per hist/partition block

using short8 = __attribute__((ext_vector_type(8))) short;
using f32x4  = __attribute__((ext_vector_type(4))) float;

// ---------------- bf16 helpers ----------------

__device__ __forceinline__ unsigned short f2bf(float f) {
    unsigned u = __float_as_uint(f);
    unsigned r = u + 0x7FFFu + ((u >> 16) & 1u);   // round to nearest even
    return (unsigned short)(r >> 16);
}
__device__ __forceinline__ float bf2f(unsigned short h) {
    return __uint_as_float(((unsigned)h) << 16);
}

// ---------------- CSR build: atomic-free radix partition ----------------

__global__ __launch_bounds__(256) void hist_kernel(const int* __restrict__ dst,
                                                   int* __restrict__ hist, int E) {
    __shared__ int lh[NBKT];
    int tid = threadIdx.x;
    if (tid < NBKT) lh[tid] = 0;
    __syncthreads();
    int e0 = blockIdx.x * CHUNK;
    #pragma unroll
    for (int i = 0; i < CHUNK / 256; i++) {
        int e = e0 + tid + i * 256;
        if (e < E) atomicAdd(&lh[dst[e] >> NPB_SHIFT], 1);
    }
    __syncthreads();
    if (tid < NBKT) hist[(size_t)blockIdx.x * NBKT + tid] = lh[tid];
}

__global__ __launch_bounds__(64) void scan_cols_kernel(const int* __restrict__ hist,
                                                       int* __restrict__ offsT,
                                                       int* __restrict__ btot, int B) {
    int k = blockIdx.x;
    int lane = threadIdx.x;
    int running = 0;
    for (int b0 = 0; b0 < B; b0 += 64) {
        int b = b0 + lane;
        int v = (b < B) ? hist[(size_t)b * NBKT + k] : 0;
        int iv = v;
        #pragma unroll
        for (int d = 1; d < 64; d <<= 1) {
            int x = __shfl_up(iv, d, 64);
            if (lane >= d) iv += x;
        }
        if (b < B) offsT[(size_t)k * B + b] = running + iv - v;   // exclusive
        running += __shfl(iv, 63, 64);
    }
    if (lane == 0) btot[k] = running;
}

__global__ void bucket_base_kernel(const int* __restrict__ btot,
                                   int* __restrict__ bbase,
                                   int* __restrict__ rowptr, int n) {
    if (threadIdx.x == 0 && blockIdx.x == 0) {
        int run = 0;
        for (int i = 0; i < NBKT; i++) { bbase[i] = run; run += btot[i]; }
        bbase[NBKT] = run;
        rowptr[n] = run;
    }
}

__global__ __launch_bounds__(256) void partition_kernel(const int* __restrict__ src,
                                                        const int* __restrict__ dst,
                                                        const int* __restrict__ bbase,
                                                        const int* __restrict__ offsT,
                                                        int2* __restrict__ epair,
                                                        int E, int B) {
    __shared__ int cur[NBKT];
    int blk = blockIdx.x, tid = threadIdx.x;
    if (tid < NBKT) cur[tid] = bbase[tid] + offsT[(size_t)tid * B + blk];
    __syncthreads();
    int e0 = blk * CHUNK;
    #pragma unroll
    for (int i = 0; i < CHUNK / 256; i++) {
        int e = e0 + tid + i * 256;
        if (e < E) {
            int d = dst[e];
            int s = src[e];
            int pos = atomicAdd(&cur[d >> NPB_SHIFT], 1);
            epair[pos] = make_int2(s, d);
        }
    }
}

__global__ __launch_bounds__(512) void csr_build_kernel(const int2* __restrict__ epair,
                                                        const int* __restrict__ bbase,
                                                        int* __restrict__ rowptr,
                                                        float* __restrict__ dis,
                                                        int* __restrict__ csrc, int n) {
    __shared__ int lcount[NPB];
    __shared__ int lcur[NPB];
    __shared__ int wsums[8];
    int k = blockIdx.x, tid = threadIdx.x;
    int lane = tid & 63, wid = tid >> 6;
    int nodebase = k << NPB_SHIFT;
    int ebeg = bbase[k], eend = bbase[k + 1];

    lcount[tid] = 0;
    __syncthreads();
    for (int e = ebeg + tid; e < eend; e += 512)
        atomicAdd(&lcount[epair[e].y - nodebase], 1);
    __syncthreads();

    int v = lcount[tid];
    int iv = v;
    #pragma unroll
    for (int d = 1; d < 64; d <<= 1) {
        int x = __shfl_up(iv, d, 64);
        if (lane >= d) iv += x;
    }
    if (lane == 63) wsums[wid] = iv;
    __syncthreads();
    if (tid == 0) {
        int r = 0;
        #pragma unroll
        for (int w = 0; w < 8; w++) { int t = wsums[w]; wsums[w] = r; r += t; }
    }
    __syncthreads();
    int ex = wsums[wid] + iv - v;
    lcur[tid] = ex;
    int node = nodebase + tid;
    if (node < n) {
        rowptr[node] = ebeg + ex;
        dis[node] = rsqrtf((float)(v + 1));      // deg = indeg + self-loop
    }
    __syncthreads();
    for (int e = ebeg + tid; e < eend; e += 512) {
        int2 p = epair[e];
        int pos = atomicAdd(&lcur[p.y - nodebase], 1);
        csrc[ebeg + pos] = p.x;
    }
}

// ---------------- layer 0: 5-dim scaled copy + aggregation ----------------

__global__ __launch_bounds__(256) void xscale_kernel(const float* __restrict__ x,
                                                     const float* __restrict__ dis,
                                                     float* __restrict__ xsp, int n) {
    int i = blockIdx.x * 256 + threadIdx.x;
    if (i >= n) return;
    float di = dis[i];
    float4 a;
    a.x = x[(size_t)i * 5 + 0] * di;
    a.y = x[(size_t)i * 5 + 1] * di;
    a.z = x[(size_t)i * 5 + 2] * di;
    a.w = x[(size_t)i * 5 + 3] * di;
    float a4 = x[(size_t)i * 5 + 4] * di;
    ((float4*)(xsp + (size_t)i * 8))[0] = a;
    xsp[(size_t)i * 8 + 4] = a4;
}

__global__ __launch_bounds__(256) void aggx_kernel(const float* __restrict__ xsp,
                                                   const float* __restrict__ dis,
                                                   const int* __restrict__ rowptr,
                                                   const int* __restrict__ csrc,
                                                   float* __restrict__ a0p, int n) {
    int i = blockIdx.x * 256 + threadIdx.x;
    if (i >= n) return;
    float4 acc = ((const float4*)(xsp + (size_t)i * 8))[0];
    float acc4 = xsp[(size_t)i * 8 + 4];
    int r0 = rowptr[i], r1 = rowptr[i + 1];
    for (int e = r0; e < r1; e++) {
        int s = csrc[e];
        float4 v = ((const float4*)(xsp + (size_t)s * 8))[0];
        acc.x += v.x; acc.y += v.y; acc.z += v.z; acc.w += v.w;
        acc4 += xsp[(size_t)s * 8 + 4];
    }
    float di = dis[i];
    acc.x *= di; acc.y *= di; acc.z *= di; acc.w *= di; acc4 *= di;
    ((float4*)(a0p + (size_t)i * 8))[0] = acc;
    a0p[(size_t)i * 8 + 4] = acc4;
}

// ------- fused mm (MFMA): t1 = bf16( dis ⊙ (relu(a0@W0 + b0) @ W1) ) -------
// 128 rows/block, 4 waves. A = h1 (bf16, LDS, XOR-swizzled), B = W1^T (bf16,
// LDS, XOR-swizzled). mfma_f32_16x16x32_bf16; C/D: col=lane&15, row=(lane>>4)*4+reg.

__global__ __launch_bounds__(256) void mmfused_kernel(const float* __restrict__ a0p,
                                                      const float* __restrict__ W0,
                                                      const float* __restrict__ b0,
                                                      const float* __restrict__ W1,
                                                      const float* __restrict__ dis,
                                                      unsigned short* __restrict__ t1b, int n) {
    __shared__ __align__(16) unsigned short sA[128 * 128];   // 32 KB h1 / reused for out
    __shared__ __align__(16) unsigned short sBT[128 * 128];  // 32 KB W1^T
    __shared__ __align__(16) float4 sA0[256];                // 4 KB a0p rows
    __shared__ float sDis[128];
    char* sAb = (char*)sA;
    char* sBb = (char*)sBT;
    int tid = threadIdx.x;
    int rowBase = blockIdx.x * 128;

    // stage a0p rows + dis
    {
        int rowL = tid >> 1, q = tid & 1;
        int gr = rowBase + rowL;
        float4 v = make_float4(0.f, 0.f, 0.f, 0.f);
        if (gr < n) v = ((const float4*)a0p)[(size_t)gr * 2 + q];
        sA0[tid] = v;
        if (tid < 128) {
            int g2 = rowBase + tid;
            sDis[tid] = (g2 < n) ? dis[g2] : 0.f;
        }
    }
    // stage W1 -> sBT[col][k] bf16, swizzled
    for (int idx = tid; idx < 128 * 32; idx += 256) {
        int k = idx >> 5, c4 = idx & 31;
        float4 w = ((const float4*)W1)[idx];
        int col0 = c4 * 4;
        float wv[4] = {w.x, w.y, w.z, w.w};
        #pragma unroll
        for (int j = 0; j < 4; j++) {
            int col = col0 + j;
            int byteoff = (col * 256 + k * 2) ^ ((col & 7) << 4);
            *(unsigned short*)(sBb + byteoff) = f2bf(wv[j]);
        }
    }
    __syncthreads();

    // h1 = relu(a0 @ W0 + b0) -> sA bf16, swizzled. thread: 4 fixed cols x 16 rows.
    {
        int cq = tid & 31;          // col quad: cols cq*4..cq*4+3
        int rg = tid >> 5;          // row group 0..7
        float4 w0q[5];
        #pragma unroll
        for (int j = 0; j < 5; j++) w0q[j] = *((const float4*)(W0 + j * 128 + cq * 4));
        float4 b0q = *((const float4*)(b0 + cq * 4));
        const float* sA0f = (const float*)sA0;
        #pragma unroll
        for (int ri = 0; ri < 16; ri++) {
            int row = rg + ri * 8;
            const float* ar = sA0f + row * 8;
            float4 h = b0q;
            #pragma unroll
            for (int j = 0; j < 5; j++) {
                float aj = ar[j];
                h.x = fmaf(aj, w0q[j].x, h.x);
                h.y = fmaf(aj, w0q[j].y, h.y);
                h.z = fmaf(aj, w0q[j].z, h.z);
                h.w = fmaf(aj, w0q[j].w, h.w);
            }
            h.x = fmaxf(h.x, 0.f); h.y = fmaxf(h.y, 0.f);
            h.z = fmaxf(h.z, 0.f); h.w = fmaxf(h.w, 0.f);
            uint2 p;
            p.x = (unsigned)f2bf(h.x) | ((unsigned)f2bf(h.y) << 16);
            p.y = (unsigned)f2bf(h.z) | ((unsigned)f2bf(h.w) << 16);
            int byteoff = (row * 256 + cq * 8) ^ ((row & 7) << 4);
            *(uint2*)(sAb + byteoff) = p;
        }
    }
    __syncthreads();

    // MFMA: wave w owns rows w*32 .. w*32+31
    int wave = tid >> 6, l = tid & 63;
    int lr = l & 15, lg = l >> 4;
    int rb = wave * 32;

    short8 afr[2][4];
    #pragma unroll
    for (int rt = 0; rt < 2; rt++) {
        int row = rb + rt * 16 + lr;
        #pragma unroll
        for (int ks = 0; ks < 4; ks++) {
            int byteoff = (row * 256 + ks * 64 + lg * 16) ^ ((row & 7) << 4);
            afr[rt][ks] = *(const short8*)(sAb + byteoff);
        }
    }
    f32x4 acc[2][8];
    #pragma unroll
    for (int rt = 0; rt < 2; rt++)
        #pragma unroll
        for (int ct = 0; ct < 8; ct++)
            acc[rt][ct] = (f32x4){0.f, 0.f, 0.f, 0.f};

    #pragma unroll
    for (int ct = 0; ct < 8; ct++) {
        int col = ct * 16 + lr;
        short8 bfr[4];
        #pragma unroll
        for (int ks = 0; ks < 4; ks++) {
            int byteoff = (col * 256 + ks * 64 + lg * 16) ^ ((col & 7) << 4);
            bfr[ks] = *(const short8*)(sBb + byteoff);
        }
        #pragma unroll
        for (int rt = 0; rt < 2; rt++) {
            #pragma unroll
            for (int ks = 0; ks < 4; ks++) {
                acc[rt][ct] = __builtin_amdgcn_mfma_f32_16x16x32_bf16(
                    afr[rt][ks], bfr[ks], acc[rt][ct], 0, 0, 0);
            }
        }
    }

    // epilogue: dis-scale, bf16, write back into own sA rows (swizzled)
    #pragma unroll
    for (int rt = 0; rt < 2; rt++) {
        #pragma unroll
        for (int i = 0; i < 4; i++) {
            int rowL = rb + rt * 16 + lg * 4 + i;
            float dsc = sDis[rowL];
            #pragma unroll
            for (int ct = 0; ct < 8; ct++) {
                int col = ct * 16 + lr;
                int byteoff = (rowL * 256 + col * 2) ^ ((rowL & 7) << 4);
                *(unsigned short*)(sAb + byteoff) = f2bf(acc[rt][ct][i] * dsc);
            }
        }
    }
    __syncthreads();

    // coalesced copy-out
    #pragma unroll
    for (int it = 0; it < 8; it++) {
        int flat = tid + it * 256;
        int rowL = flat >> 4, c16 = flat & 15;
        int gr = rowBase + rowL;
        if (gr < n) {
            int byteoff = (rowL * 256 + c16 * 16) ^ ((rowL & 7) << 4);
            uint4 v = *(const uint4*)(sAb + byteoff);
            ((uint4*)t1b)[(size_t)gr * 16 + c16] = v;
        }
    }
}

// ---------------- w2l = W2 @ lin_w, c2 = b2 . lin_w ----------------

__global__ __launch_bounds__(256) void w2l_kernel(const float* __restrict__ W2,
                                                  const float* __restrict__ b2,
                                                  const float* __restrict__ lw,
                                                  float* __restrict__ w2l,
                                                  float* __restrict__ c2) {
    __shared__ float slw[128];
    int tid = threadIdx.x;
    if (tid < 128) slw[tid] = lw[tid];
    __syncthreads();
    if (tid < 128) {
        float s = 0.f;
        #pragma unroll 8
        for (int j = 0; j < 128; j++) s = fmaf(W2[tid * 128 + j], slw[j], s);
        w2l[tid] = s;
    } else if (tid == 128) {
        float s = 0.f;
        for (int j = 0; j < 128; j++) s = fmaf(b2[j], slw[j], s);
        c2[0] = s;
    }
}

// --------- layer-1 aggregation (bf16 gather) fused with layer-2 dot ---------

__global__ __launch_bounds__(256) void agg1_kernel(const unsigned short* __restrict__ t1b,
                                                   const float* __restrict__ dis,
                                                   const int* __restrict__ rowptr,
                                                   const int* __restrict__ csrc,
                                                   const float* __restrict__ b1,
                                                   const float* __restrict__ w2l,
                                                   float* __restrict__ z, int n) {
    int group = threadIdx.x >> 5, lane = threadIdx.x & 31;
    int i = blockIdx.x * 8 + group;
    if (i >= n) return;
    const ushort4* t4 = (const ushort4*)t1b;     // 32 x ushort4 per row
    ushort4 sv = t4[(size_t)i * 32 + lane];
    float4 acc = make_float4(bf2f(sv.x), bf2f(sv.y), bf2f(sv.z), bf2f(sv.w));
    int r0 = rowptr[i], r1 = rowptr[i + 1];
    int e = r0;
    for (; e + 3 < r1; e += 4) {
        int s0 = csrc[e], s1 = csrc[e + 1], s2 = csrc[e + 2], s3 = csrc[e + 3];
        ushort4 v0 = t4[(size_t)s0 * 32 + lane];
        ushort4 v1 = t4[(size_t)s1 * 32 + lane];
        ushort4 v2 = t4[(size_t)s2 * 32 + lane];
        ushort4 v3 = t4[(size_t)s3 * 32 + lane];
        acc.x += (bf2f(v0.x) + bf2f(v1.x)) + (bf2f(v2.x) + bf2f(v3.x));
        acc.y += (bf2f(v0.y) + bf2f(v1.y)) + (bf2f(v2.y) + bf2f(v3.y));
        acc.z += (bf2f(v0.z) + bf2f(v1.z)) + (bf2f(v2.z) + bf2f(v3.z));
        acc.w += (bf2f(v0.w) + bf2f(v1.w)) + (bf2f(v2.w) + bf2f(v3.w));
    }
    for (; e < r1; e++) {
        ushort4 v = t4[(size_t)csrc[e] * 32 + lane];
        acc.x += bf2f(v.x); acc.y += bf2f(v.y);
        acc.z += bf2f(v.z); acc.w += bf2f(v.w);
    }
    float di = dis[i];
    float4 b4 = ((const float4*)b1)[lane];
    acc.x = fmaf(di, acc.x, b4.x);
    acc.y = fmaf(di, acc.y, b4.y);
    acc.z = fmaf(di, acc.z, b4.z);
    acc.w = fmaf(di, acc.w, b4.w);
    acc.x = fmaxf(acc.x, 0.f); acc.y = fmaxf(acc.y, 0.f);
    acc.z = fmaxf(acc.z, 0.f); acc.w = fmaxf(acc.w, 0.f);
    float4 w = ((const float4*)w2l)[lane];
    float d = acc.x * w.x + acc.y * w.y + acc.z * w.z + acc.w * w.w;
    #pragma unroll
    for (int o = 16; o > 0; o >>= 1) d += __shfl_down(d, o, 32);
    if (lane == 0) z[i] = di * d;
}

// ---------------- layer-2 scalar aggregation ----------------

__global__ __launch_bounds__(256) void aggz_kernel(const float* __restrict__ z,
                                                   const float* __restrict__ dis,
                                                   const int* __restrict__ rowptr,
                                                   const int* __restrict__ csrc,
                                                   float* __restrict__ nd, int n) {
    int i = blockIdx.x * 256 + threadIdx.x;
    if (i >= n) return;
    float acc = z[i];
    int r0 = rowptr[i], r1 = rowptr[i + 1];
    int e = r0;
    for (; e + 3 < r1; e += 4) {
        acc += (z[csrc[e]] + z[csrc[e + 1]]) + (z[csrc[e + 2]] + z[csrc[e + 3]]);
    }
    for (; e < r1; e++) acc += z[csrc[e]];
    nd[i] = dis[i] * acc;
}

// ---------------- pooling (segment reduce over sorted batch) ----------------

__global__ __launch_bounds__(256) void boundary_kernel(const int* __restrict__ batch,
                                                       int* __restrict__ gstart, int n) {
    int i = blockIdx.x * 256 + threadIdx.x;
    if (i >= n) return;
    int b = batch[i];
    int pb = (i == 0) ? -1 : batch[i - 1];
    for (int g = pb + 1; g <= b; g++) gstart[g] = i;
    if (i == n - 1) {
        for (int g = b + 1; g <= GCN_G; g++) gstart[g] = n;
    }
}

__global__ __launch_bounds__(256) void reduce_kernel(const float* __restrict__ nd,
                                                     const int* __restrict__ gstart,
                                                     const float* __restrict__ c2,
                                                     const float* __restrict__ lb,
                                                     float* __restrict__ out) {
    __shared__ float ssum[4];
    int g = blockIdx.x;
    int s = gstart[g], epos = gstart[g + 1];
    int tid = threadIdx.x, lane = tid & 63, wid = tid >> 6;
    float sum = 0.f;
    for (int i = s + tid; i < epos; i += 256) sum += nd[i];
    #pragma unroll
    for (int o = 32; o > 0; o >>= 1) sum += __shfl_down(sum, o, 64);
    if (lane == 0) ssum[wid] = sum;
    __syncthreads();
    if (tid == 0) {
        float tot = ssum[0] + ssum[1] + ssum[2] + ssum[3];
        float cnt = (float)max(epos - s, 1);
        float v = tot / cnt + c2[0] + lb[0];
        out[g] = 1.f / (1.f + expf(-v));
    }
}

// ---------------- launch ----------------

extern "C" void kernel_launch(void* const* d_in, const int* in_sizes, int n_in,
                              void* d_out, int out_size, void* d_ws, size_t ws_size,
                              hipStream_t stream) {
    const float* x   = (const float*)d_in[0];
    const int*   ei  = (const int*)d_in[1];
    const int*   bat = (const int*)d_in[2];
    const float* W0  = (const float*)d_in[3];
    const float* b0  = (const float*)d_in[4];
    const float* W1  = (const float*)d_in[5];
    const float* b1  = (const float*)d_in[6];
    const float* W2  = (const float*)d_in[7];
    const float* b2  = (const float*)d_in[8];
    const float* lw  = (const float*)d_in[9];
    const float* lb  = (const float*)d_in[10];
    float* out = (float*)d_out;

    const int N = GCN_N;
    const int E = in_sizes[1] / 2;
    const int B = (E + CHUNK - 1) / CHUNK;

    char* ws = (char*)d_ws;
    size_t off = 0;
    auto alloc = [&](size_t bytes) {
        size_t o = off;
        off += (bytes + 255) & ~(size_t)255;
        return o;
    };
    int*   hist    = (int*)(ws + alloc((size_t)B * NBKT * 4));
    int*   offsT   = (int*)(ws + alloc((size_t)NBKT * B * 4));
    int*   btot    = (int*)(ws + alloc((size_t)NBKT * 4));
    int*   bbase   = (int*)(ws + alloc((size_t)(NBKT + 1) * 4));
    int2*  epair   = (int2*)(ws + alloc((size_t)E * 8));
    int*   rowptr  = (int*)(ws + alloc((size_t)(N + 1) * 4));
    float* dis     = (float*)(ws + alloc((size_t)N * 4));
    int*   csrc    = (int*)(ws + alloc((size_t)E * 4));
    float* xsp     = (float*)(ws + alloc((size_t)N * 8 * 4));
    float* a0p     = (float*)(ws + alloc((size_t)N * 8 * 4));
    unsigned short* t1b = (unsigned short*)(ws + alloc((size_t)N * GCN_H * 2));
    float* z       = (float*)(ws + alloc((size_t)N * 4));
    float* nd      = (float*)(ws + alloc((size_t)N * 4));
    int*   gstart  = (int*)(ws + alloc((size_t)(GCN_G + 1) * 4));
    float* w2l     = (float*)(ws + alloc(128 * 4));
    float* c2      = (float*)(ws + alloc(4));

    const int* src = ei;
    const int* dst = ei + E;

    hist_kernel<<<B, 256, 0, stream>>>(dst, hist, E);
    scan_cols_kernel<<<NBKT, 64, 0, stream>>>(hist, offsT, btot, B);
    bucket_base_kernel<<<1, 64, 0, stream>>>(btot, bbase, rowptr, N);
    partition_kernel<<<B, 256, 0, stream>>>(src, dst, bbase, offsT, epair, E, B);
    csr_build_kernel<<<NBKT, 512, 0, stream>>>(epair, bbase, rowptr, dis, csrc, N);
    boundary_kernel<<<(N + 255) / 256, 256, 0, stream>>>(bat, gstart, N);
    w2l_kernel<<<1, 256, 0, stream>>>(W2, b2, lw, w2l, c2);

    xscale_kernel<<<(N + 255) / 256, 256, 0, stream>>>(x, dis, xsp, N);
    aggx_kernel<<<(N + 255) / 256, 256, 0, stream>>>(xsp, dis, rowptr, csrc, a0p, N);
    mmfused_kernel<<<(N + 127) / 128, 256, 0, stream>>>(a0p, W0, b0, W1, dis, t1b, N);
    agg1_kernel<<<N / 8, 256, 0, stream>>>(t1b, dis, rowptr, csrc, b1, w2l, z, N);
    aggz_kernel<<<(N + 255) / 256, 256, 0, stream>>>(z, dis, rowptr, csrc, nd, N);

    reduce_kernel<<<GCN_G, 256, 0, stream>>>(nd, gstart, c2, lb, out);
}

// Round 7
// 170.798 us; speedup vs baseline: 5.8277x; 1.1117x over previous
//
#include <hip/hip_runtime.h>
#include <hip/hip_fp8.h>

#define GCN_N 100000
#define GCN_H 128
#define GCN_G 256
#define NPB_SHIFT 9                    // 512 nodes per bucket
#define NPB 512
#define NBKT 196                       // ceil(100000/512)
#define CHUNK 2048                     // edges per hist/partition block
#define SRC_BITS 17
#define SRC_MASK ((1 << SRC_BITS) - 1)
#define T1_SCALE 256.0f
#define T1_INV_SCALE (1.0f / 256.0f)

static_assert(GCN_N < (1 << SRC_BITS), "src id must fit 17 bits");

using short8 = __attribute__((ext_vector_type(8))) short;
using f32x4  = __attribute__((ext_vector_type(4))) float;
using f32x2  = __attribute__((ext_vector_type(2))) float;

#if defined(__has_builtin)
#if __has_builtin(__builtin_amdgcn_cvt_pk_f32_fp8) && __has_builtin(__builtin_amdgcn_cvt_pk_fp8_f32)
#define HW_FP8 1
#endif
#endif

// ---------------- bf16 / fp8 helpers ----------------

__device__ __forceinline__ unsigned short f2bf(float f) {
    unsigned u = __float_as_uint(f);
    unsigned r = u + 0x7FFFu + ((u >> 16) & 1u);   // round to nearest even
    return (unsigned short)(r >> 16);
}
__device__ __forceinline__ float bf2f(unsigned short h) {
    return __uint_as_float(((unsigned)h) << 16);
}

// decode 4 fp8(e4m3) packed in a dword -> 4 floats
__device__ __forceinline__ void fp8x4_to_f32(unsigned v, float* f) {
#ifdef HW_FP8
    f32x2 lo = __builtin_amdgcn_cvt_pk_f32_fp8((int)v, false);
    f32x2 hi = __builtin_amdgcn_cvt_pk_f32_fp8((int)v, true);
    f[0] = lo[0]; f[1] = lo[1]; f[2] = hi[0]; f[3] = hi[1];
#else
    #pragma unroll
    for (int j = 0; j < 4; j++) {
        __hip_fp8_e4m3 h;
        h.__x = (unsigned char)((v >> (8 * j)) & 0xFF);
        f[j] = (float)h;
    }
#endif
}

// encode 4 floats -> dword of 4 fp8(e4m3)
__device__ __forceinline__ unsigned f32x4_to_fp8(float f0, float f1, float f2, float f3) {
#ifdef HW_FP8
    int r = __builtin_amdgcn_cvt_pk_fp8_f32(f0, f1, 0, false);
    r = __builtin_amdgcn_cvt_pk_fp8_f32(f2, f3, r, true);
    return (unsigned)r;
#else
    unsigned r = 0;
    float ff[4] = {f0, f1, f2, f3};
    #pragma unroll
    for (int j = 0; j < 4; j++) {
        __hip_fp8_e4m3 h(ff[j]);
        r |= ((unsigned)h.__x) << (8 * j);
    }
    return r;
#endif
}

// ---------------- CSR build: atomic-free radix partition ----------------

__global__ __launch_bounds__(256) void hist_kernel(const int* __restrict__ dst,
                                                   int* __restrict__ hist, int E) {
    __shared__ int lh[NBKT];
    int tid = threadIdx.x;
    if (tid < NBKT) lh[tid] = 0;
    __syncthreads();
    int e0 = blockIdx.x * CHUNK;
    #pragma unroll
    for (int i = 0; i < CHUNK / 256; i++) {
        int e = e0 + tid + i * 256;
        if (e < E) atomicAdd(&lh[dst[e] >> NPB_SHIFT], 1);
    }
    __syncthreads();
    if (tid < NBKT) hist[(size_t)blockIdx.x * NBKT + tid] = lh[tid];
}

__global__ __launch_bounds__(64) void scan_cols_kernel(const int* __restrict__ hist,
                                                       int* __restrict__ offsT,
                                                       int* __restrict__ btot, int B) {
    int k = blockIdx.x;
    int lane = threadIdx.x;
    int running = 0;
    for (int b0 = 0; b0 < B; b0 += 64) {
        int b = b0 + lane;
        int v = (b < B) ? hist[(size_t)b * NBKT + k] : 0;
        int iv = v;
        #pragma unroll
        for (int d = 1; d < 64; d <<= 1) {
            int x = __shfl_up(iv, d, 64);
            if (lane >= d) iv += x;
        }
        if (b < B) offsT[(size_t)k * B + b] = running + iv - v;   // exclusive
        running += __shfl(iv, 63, 64);
    }
    if (lane == 0) btot[k] = running;
}

__global__ void bucket_base_kernel(const int* __restrict__ btot,
                                   int* __restrict__ bbase,
                                   int* __restrict__ rowptr, int n) {
    if (threadIdx.x == 0 && blockIdx.x == 0) {
        int run = 0;
        for (int i = 0; i < NBKT; i++) { bbase[i] = run; run += btot[i]; }
        bbase[NBKT] = run;
        rowptr[n] = run;
    }
}

// pack (local_dst << 17) | src into one int
__global__ __launch_bounds__(256) void partition_kernel(const int* __restrict__ src,
                                                        const int* __restrict__ dst,
                                                        const int* __restrict__ bbase,
                                                        const int* __restrict__ offsT,
                                                        int* __restrict__ epack,
                                                        int E, int B) {
    __shared__ int cur[NBKT];
    int blk = blockIdx.x, tid = threadIdx.x;
    if (tid < NBKT) cur[tid] = bbase[tid] + offsT[(size_t)tid * B + blk];
    __syncthreads();
    int e0 = blk * CHUNK;
    #pragma unroll
    for (int i = 0; i < CHUNK / 256; i++) {
        int e = e0 + tid + i * 256;
        if (e < E) {
            int d = dst[e];
            int s = src[e];
            int pos = atomicAdd(&cur[d >> NPB_SHIFT], 1);
            epack[pos] = ((d & (NPB - 1)) << SRC_BITS) | s;
        }
    }
}

__global__ __launch_bounds__(512) void csr_build_kernel(const int* __restrict__ epack,
                                                        const int* __restrict__ bbase,
                                                        int* __restrict__ rowptr,
                                                        float* __restrict__ dis,
                                                        int* __restrict__ csrc, int n) {
    __shared__ int lcount[NPB];
    __shared__ int lcur[NPB];
    __shared__ int wsums[8];
    int k = blockIdx.x, tid = threadIdx.x;
    int lane = tid & 63, wid = tid >> 6;
    int nodebase = k << NPB_SHIFT;
    int ebeg = bbase[k], eend = bbase[k + 1];

    lcount[tid] = 0;
    __syncthreads();
    for (int e = ebeg + tid; e < eend; e += 512)
        atomicAdd(&lcount[epack[e] >> SRC_BITS], 1);
    __syncthreads();

    int v = lcount[tid];
    int iv = v;
    #pragma unroll
    for (int d = 1; d < 64; d <<= 1) {
        int x = __shfl_up(iv, d, 64);
        if (lane >= d) iv += x;
    }
    if (lane == 63) wsums[wid] = iv;
    __syncthreads();
    if (tid == 0) {
        int r = 0;
        #pragma unroll
        for (int w = 0; w < 8; w++) { int t = wsums[w]; wsums[w] = r; r += t; }
    }
    __syncthreads();
    int ex = wsums[wid] + iv - v;
    lcur[tid] = ex;
    int node = nodebase + tid;
    if (node < n) {
        rowptr[node] = ebeg + ex;
        dis[node] = rsqrtf((float)(v + 1));      // deg = indeg + self-loop
    }
    __syncthreads();
    for (int e = ebeg + tid; e < eend; e += 512) {
        int p = epack[e];
        int pos = atomicAdd(&lcur[p >> SRC_BITS], 1);
        csrc[ebeg + pos] = p & SRC_MASK;
    }
}

// ---------------- layer 0: 5-dim scaled copy + aggregation ----------------

__global__ __launch_bounds__(256) void xscale_kernel(const float* __restrict__ x,
                                                     const float* __restrict__ dis,
                                                     float* __restrict__ xsp, int n) {
    int i = blockIdx.x * 256 + threadIdx.x;
    if (i >= n) return;
    float di = dis[i];
    float4 a;
    a.x = x[(size_t)i * 5 + 0] * di;
    a.y = x[(size_t)i * 5 + 1] * di;
    a.z = x[(size_t)i * 5 + 2] * di;
    a.w = x[(size_t)i * 5 + 3] * di;
    float a4 = x[(size_t)i * 5 + 4] * di;
    ((float4*)(xsp + (size_t)i * 8))[0] = a;
    xsp[(size_t)i * 8 + 4] = a4;
}

__global__ __launch_bounds__(256) void aggx_kernel(const float* __restrict__ xsp,
                                                   const float* __restrict__ dis,
                                                   const int* __restrict__ rowptr,
                                                   const int* __restrict__ csrc,
                                                   float* __restrict__ a0p, int n) {
    int i = blockIdx.x * 256 + threadIdx.x;
    if (i >= n) return;
    float4 acc = ((const float4*)(xsp + (size_t)i * 8))[0];
    float acc4 = xsp[(size_t)i * 8 + 4];
    int r0 = rowptr[i], r1 = rowptr[i + 1];
    for (int e = r0; e < r1; e++) {
        int s = csrc[e];
        float4 v = ((const float4*)(xsp + (size_t)s * 8))[0];
        acc.x += v.x; acc.y += v.y; acc.z += v.z; acc.w += v.w;
        acc4 += xsp[(size_t)s * 8 + 4];
    }
    float di = dis[i];
    acc.x *= di; acc.y *= di; acc.z *= di; acc.w *= di; acc4 *= di;
    ((float4*)(a0p + (size_t)i * 8))[0] = acc;
    a0p[(size_t)i * 8 + 4] = acc4;
}

// ------- fused mm (MFMA): t1 = fp8( 256 * dis ⊙ (relu(a0@W0 + b0) @ W1) ) -------

__global__ __launch_bounds__(256) void mmfused_kernel(const float* __restrict__ a0p,
                                                      const float* __restrict__ W0,
                                                      const float* __restrict__ b0,
                                                      const float* __restrict__ W1,
                                                      const float* __restrict__ dis,
                                                      unsigned* __restrict__ t1f8, int n) {
    __shared__ __align__(16) unsigned short sA[128 * 128];   // 32 KB h1 / reused for out
    __shared__ __align__(16) unsigned short sBT[128 * 128];  // 32 KB W1^T
    __shared__ __align__(16) float4 sA0[256];                // 4 KB a0p rows
    __shared__ float sDis[128];
    char* sAb = (char*)sA;
    char* sBb = (char*)sBT;
    int tid = threadIdx.x;
    int rowBase = blockIdx.x * 128;

    // stage a0p rows + dis
    {
        int rowL = tid >> 1, q = tid & 1;
        int gr = rowBase + rowL;
        float4 v = make_float4(0.f, 0.f, 0.f, 0.f);
        if (gr < n) v = ((const float4*)a0p)[(size_t)gr * 2 + q];
        sA0[tid] = v;
        if (tid < 128) {
            int g2 = rowBase + tid;
            sDis[tid] = (g2 < n) ? dis[g2] : 0.f;
        }
    }
    // stage W1 -> sBT[col][k] bf16, swizzled
    for (int idx = tid; idx < 128 * 32; idx += 256) {
        int k = idx >> 5, c4 = idx & 31;
        float4 w = ((const float4*)W1)[idx];
        int col0 = c4 * 4;
        float wv[4] = {w.x, w.y, w.z, w.w};
        #pragma unroll
        for (int j = 0; j < 4; j++) {
            int col = col0 + j;
            int byteoff = (col * 256 + k * 2) ^ ((col & 7) << 4);
            *(unsigned short*)(sBb + byteoff) = f2bf(wv[j]);
        }
    }
    __syncthreads();

    // h1 = relu(a0 @ W0 + b0) -> sA bf16, swizzled. thread: 4 fixed cols x 16 rows.
    {
        int cq = tid & 31;          // col quad: cols cq*4..cq*4+3
        int rg = tid >> 5;          // row group 0..7
        float4 w0q[5];
        #pragma unroll
        for (int j = 0; j < 5; j++) w0q[j] = *((const float4*)(W0 + j * 128 + cq * 4));
        float4 b0q = *((const float4*)(b0 + cq * 4));
        const float* sA0f = (const float*)sA0;
        #pragma unroll
        for (int ri = 0; ri < 16; ri++) {
            int row = rg + ri * 8;
            const float* ar = sA0f + row * 8;
            float4 h = b0q;
            #pragma unroll
            for (int j = 0; j < 5; j++) {
                float aj = ar[j];
                h.x = fmaf(aj, w0q[j].x, h.x);
                h.y = fmaf(aj, w0q[j].y, h.y);
                h.z = fmaf(aj, w0q[j].z, h.z);
                h.w = fmaf(aj, w0q[j].w, h.w);
            }
            h.x = fmaxf(h.x, 0.f); h.y = fmaxf(h.y, 0.f);
            h.z = fmaxf(h.z, 0.f); h.w = fmaxf(h.w, 0.f);
            uint2 p;
            p.x = (unsigned)f2bf(h.x) | ((unsigned)f2bf(h.y) << 16);
            p.y = (unsigned)f2bf(h.z) | ((unsigned)f2bf(h.w) << 16);
            int byteoff = (row * 256 + cq * 8) ^ ((row & 7) << 4);
            *(uint2*)(sAb + byteoff) = p;
        }
    }
    __syncthreads();

    // MFMA: wave w owns rows w*32 .. w*32+31
    int wave = tid >> 6, l = tid & 63;
    int lr = l & 15, lg = l >> 4;
    int rb = wave * 32;

    short8 afr[2][4];
    #pragma unroll
    for (int rt = 0; rt < 2; rt++) {
        int row = rb + rt * 16 + lr;
        #pragma unroll
        for (int ks = 0; ks < 4; ks++) {
            int byteoff = (row * 256 + ks * 64 + lg * 16) ^ ((row & 7) << 4);
            afr[rt][ks] = *(const short8*)(sAb + byteoff);
        }
    }
    f32x4 acc[2][8];
    #pragma unroll
    for (int rt = 0; rt < 2; rt++)
        #pragma unroll
        for (int ct = 0; ct < 8; ct++)
            acc[rt][ct] = (f32x4){0.f, 0.f, 0.f, 0.f};

    #pragma unroll
    for (int ct = 0; ct < 8; ct++) {
        int col = ct * 16 + lr;
        short8 bfr[4];
        #pragma unroll
        for (int ks = 0; ks < 4; ks++) {
            int byteoff = (col * 256 + ks * 64 + lg * 16) ^ ((col & 7) << 4);
            bfr[ks] = *(const short8*)(sBb + byteoff);
        }
        #pragma unroll
        for (int rt = 0; rt < 2; rt++) {
            #pragma unroll
            for (int ks = 0; ks < 4; ks++) {
                acc[rt][ct] = __builtin_amdgcn_mfma_f32_16x16x32_bf16(
                    afr[rt][ks], bfr[ks], acc[rt][ct], 0, 0, 0);
            }
        }
    }

    // epilogue: dis*256-scale, bf16, write back into own sA rows (swizzled)
    #pragma unroll
    for (int rt = 0; rt < 2; rt++) {
        #pragma unroll
        for (int i = 0; i < 4; i++) {
            int rowL = rb + rt * 16 + lg * 4 + i;
            float dsc = sDis[rowL] * T1_SCALE;
            #pragma unroll
            for (int ct = 0; ct < 8; ct++) {
                int col = ct * 16 + lr;
                int byteoff = (rowL * 256 + col * 2) ^ ((rowL & 7) << 4);
                *(unsigned short*)(sAb + byteoff) = f2bf(acc[rt][ct][i] * dsc);
            }
        }
    }
    __syncthreads();

    // copy-out with bf16 -> fp8 conversion (8 cols per thread)
    #pragma unroll
    for (int it = 0; it < 8; it++) {
        int flat = tid + it * 256;
        int rowL = flat >> 4, c16 = flat & 15;
        int gr = rowBase + rowL;
        if (gr < n) {
            int byteoff = (rowL * 256 + c16 * 16) ^ ((rowL & 7) << 4);
            uint4 v = *(const uint4*)(sAb + byteoff);
            float f0 = __uint_as_float(v.x << 16), f1 = __uint_as_float(v.x & 0xFFFF0000u);
            float f2 = __uint_as_float(v.y << 16), f3 = __uint_as_float(v.y & 0xFFFF0000u);
            float f4 = __uint_as_float(v.z << 16), f5 = __uint_as_float(v.z & 0xFFFF0000u);
            float f6 = __uint_as_float(v.w << 16), f7 = __uint_as_float(v.w & 0xFFFF0000u);
            uint2 p;
            p.x = f32x4_to_fp8(f0, f1, f2, f3);
            p.y = f32x4_to_fp8(f4, f5, f6, f7);
            ((uint2*)t1f8)[(size_t)gr * 16 + c16] = p;
        }
    }
}

// ---------------- w2l = W2 @ lin_w, c2 = b2 . lin_w ----------------

__global__ __launch_bounds__(256) void w2l_kernel(const float* __restrict__ W2,
                                                  const float* __restrict__ b2,
                                                  const float* __restrict__ lw,
                                                  float* __restrict__ w2l,
                                                  float* __restrict__ c2) {
    __shared__ float slw[128];
    int tid = threadIdx.x;
    if (tid < 128) slw[tid] = lw[tid];
    __syncthreads();
    if (tid < 128) {
        float s = 0.f;
        #pragma unroll 8
        for (int j = 0; j < 128; j++) s = fmaf(W2[tid * 128 + j], slw[j], s);
        w2l[tid] = s;
    } else if (tid == 128) {
        float s = 0.f;
        for (int j = 0; j < 128; j++) s = fmaf(b2[j], slw[j], s);
        c2[0] = s;
    }
}

// --------- layer-1 aggregation (fp8 gather) fused with layer-2 dot ---------
// conv1 = (di/256)*(t1'[i] + sum t1'[src]) + b1 ; z = di*dot(relu(conv1), w2l)

__global__ __launch_bounds__(256) void agg1_kernel(const unsigned* __restrict__ t1f8,
                                                   const float* __restrict__ dis,
                                                   const int* __restrict__ rowptr,
                                                   const int* __restrict__ csrc,
                                                   const float* __restrict__ b1,
                                                   const float* __restrict__ w2l,
                                                   float* __restrict__ z, int n) {
    int group = threadIdx.x >> 5, lane = threadIdx.x & 31;
    int i = blockIdx.x * 8 + group;
    if (i >= n) return;
    float f[4];
    unsigned sv = t1f8[(size_t)i * 32 + lane];
    fp8x4_to_f32(sv, f);
    float4 acc = make_float4(f[0], f[1], f[2], f[3]);
    int r0 = rowptr[i], r1 = rowptr[i + 1];
    int e = r0;
    for (; e + 7 < r1; e += 8) {
        unsigned vv[8];
        #pragma unroll
        for (int u = 0; u < 8; u++) vv[u] = t1f8[(size_t)csrc[e + u] * 32 + lane];
        #pragma unroll
        for (int u = 0; u < 8; u++) {
            fp8x4_to_f32(vv[u], f);
            acc.x += f[0]; acc.y += f[1]; acc.z += f[2]; acc.w += f[3];
        }
    }
    for (; e < r1; e++) {
        unsigned v = t1f8[(size_t)csrc[e] * 32 + lane];
        fp8x4_to_f32(v, f);
        acc.x += f[0]; acc.y += f[1]; acc.z += f[2]; acc.w += f[3];
    }
    float di = dis[i];
    float dis_s = di * T1_INV_SCALE;
    float4 b4 = ((const float4*)b1)[lane];
    acc.x = fmaf(dis_s, acc.x, b4.x);
    acc.y = fmaf(dis_s, acc.y, b4.y);
    acc.z = fmaf(dis_s, acc.z, b4.z);
    acc.w = fmaf(dis_s, acc.w, b4.w);
    acc.x = fmaxf(acc.x, 0.f); acc.y = fmaxf(acc.y, 0.f);
    acc.z = fmaxf(acc.z, 0.f); acc.w = fmaxf(acc.w, 0.f);
    float4 w = ((const float4*)w2l)[lane];
    float d = acc.x * w.x + acc.y * w.y + acc.z * w.z + acc.w * w.w;
    #pragma unroll
    for (int o = 16; o > 0; o >>= 1) d += __shfl_down(d, o, 32);
    if (lane == 0) z[i] = di * d;
}

// ---------------- layer-2 scalar aggregation ----------------

__global__ __launch_bounds__(256) void aggz_kernel(const float* __restrict__ z,
                                                   const float* __restrict__ dis,
                                                   const int* __restrict__ rowptr,
                                                   const int* __restrict__ csrc,
                                                   float* __restrict__ nd, int n) {
    int i = blockIdx.x * 256 + threadIdx.x;
    if (i >= n) return;
    float acc = z[i];
    int r0 = rowptr[i], r1 = rowptr[i + 1];
    int e = r0;
    for (; e + 3 < r1; e += 4) {
        acc += (z[csrc[e]] + z[csrc[e + 1]]) + (z[csrc[e + 2]] + z[csrc[e + 3]]);
    }
    for (; e < r1; e++) acc += z[csrc[e]];
    nd[i] = dis[i] * acc;
}

// ---------------- pooling (segment reduce over sorted batch) ----------------

__global__ __launch_bounds__(256) void boundary_kernel(const int* __restrict__ batch,
                                                       int* __restrict__ gstart, int n) {
    int i = blockIdx.x * 256 + threadIdx.x;
    if (i >= n) return;
    int b = batch[i];
    int pb = (i == 0) ? -1 : batch[i - 1];
    for (int g = pb + 1; g <= b; g++) gstart[g] = i;
    if (i == n - 1) {
        for (int g = b + 1; g <= GCN_G; g++) gstart[g] = n;
    }
}

__global__ __launch_bounds__(256) void reduce_kernel(const float* __restrict__ nd,
                                                     const int* __restrict__ gstart,
                                                     const float* __restrict__ c2,
                                                     const float* __restrict__ lb,
                                                     float* __restrict__ out) {
    __shared__ float ssum[4];
    int g = blockIdx.x;
    int s = gstart[g], epos = gstart[g + 1];
    int tid = threadIdx.x, lane = tid & 63, wid = tid >> 6;
    float sum = 0.f;
    for (int i = s + tid; i < epos; i += 256) sum += nd[i];
    #pragma unroll
    for (int o = 32; o > 0; o >>= 1) sum += __shfl_down(sum, o, 64);
    if (lane == 0) ssum[wid] = sum;
    __syncthreads();
    if (tid == 0) {
        float tot = ssum[0] + ssum[1] + ssum[2] + ssum[3];
        float cnt = (float)max(epos - s, 1);
        float v = tot / cnt + c2[0] + lb[0];
        out[g] = 1.f / (1.f + expf(-v));
    }
}

// ---------------- launch ----------------

extern "C" void kernel_launch(void* const* d_in, const int* in_sizes, int n_in,
                              void* d_out, int out_size, void* d_ws, size_t ws_size,
                              hipStream_t stream) {
    const float* x   = (const float*)d_in[0];
    const int*   ei  = (const int*)d_in[1];
    const int*   bat = (const int*)d_in[2];
    const float* W0  = (const float*)d_in[3];
    const float* b0  = (const float*)d_in[4];
    const float* W1  = (const float*)d_in[5];
    const float* b1  = (const float*)d_in[6];
    const float* W2  = (const float*)d_in[7];
    const float* b2  = (const float*)d_in[8];
    const float* lw  = (const float*)d_in[9];
    const float* lb  = (const float*)d_in[10];
    float* out = (float*)d_out;

    const int N = GCN_N;
    const int E = in_sizes[1] / 2;
    const int B = (E + CHUNK - 1) / CHUNK;

    char* ws = (char*)d_ws;
    size_t off = 0;
    auto alloc = [&](size_t bytes) {
        size_t o = off;
        off += (bytes + 255) & ~(size_t)255;
        return o;
    };
    int*   hist    = (int*)(ws + alloc((size_t)B * NBKT * 4));
    int*   offsT   = (int*)(ws + alloc((size_t)NBKT * B * 4));
    int*   btot    = (int*)(ws + alloc((size_t)NBKT * 4));
    int*   bbase   = (int*)(ws + alloc((size_t)(NBKT + 1) * 4));
    int*   epack   = (int*)(ws + alloc((size_t)E * 4));
    int*   rowptr  = (int*)(ws + alloc((size_t)(N + 1) * 4));
    float* dis     = (float*)(ws + alloc((size_t)N * 4));
    int*   csrc    = (int*)(ws + alloc((size_t)E * 4));
    float* xsp     = (float*)(ws + alloc((size_t)N * 8 * 4));
    float* a0p     = (float*)(ws + alloc((size_t)N * 8 * 4));
    unsigned* t1f8 = (unsigned*)(ws + alloc((size_t)N * GCN_H));
    float* z       = (float*)(ws + alloc((size_t)N * 4));
    float* nd      = (float*)(ws + alloc((size_t)N * 4));
    int*   gstart  = (int*)(ws + alloc((size_t)(GCN_G + 1) * 4));
    float* w2l     = (float*)(ws + alloc(128 * 4));
    float* c2      = (float*)(ws + alloc(4));

    const int* src = ei;
    const int* dst = ei + E;

    hist_kernel<<<B, 256, 0, stream>>>(dst, hist, E);
    scan_cols_kernel<<<NBKT, 64, 0, stream>>>(hist, offsT, btot, B);
    bucket_base_kernel<<<1, 64, 0, stream>>>(btot, bbase, rowptr, N);
    partition_kernel<<<B, 256, 0, stream>>>(src, dst, bbase, offsT, epack, E, B);
    csr_build_kernel<<<NBKT, 512, 0, stream>>>(epack, bbase, rowptr, dis, csrc, N);
    boundary_kernel<<<(N + 255) / 256, 256, 0, stream>>>(bat, gstart, N);
    w2l_kernel<<<1, 256, 0, stream>>>(W2, b2, lw, w2l, c2);

    xscale_kernel<<<(N + 255) / 256, 256, 0, stream>>>(x, dis, xsp, N);
    aggx_kernel<<<(N + 255) / 256, 256, 0, stream>>>(xsp, dis, rowptr, csrc, a0p, N);
    mmfused_kernel<<<(N + 127) / 128, 256, 0, stream>>>(a0p, W0, b0, W1, dis, t1f8, N);
    agg1_kernel<<<N / 8, 256, 0, stream>>>(t1f8, dis, rowptr, csrc, b1, w2l, z, N);
    aggz_kernel<<<(N + 255) / 256, 256, 0, stream>>>(z, dis, rowptr, csrc, nd, N);

    reduce_kernel<<<GCN_G, 256, 0, stream>>>(nd, gstart, c2, lb, out);
}

// Round 8
// 151.974 us; speedup vs baseline: 6.5496x; 1.1239x over previous
//
#include <hip/hip_runtime.h>
#include <hip/hip_fp8.h>

#define GCN_N 100000
#define GCN_H 128
#define GCN_G 256
#define NPB_SHIFT 9                    // 512 nodes per bucket
#define NPB 512
#define NBKT 196                       // ceil(100000/512)
#define CHUNK 2048                     // edges per hist/partition block
#define SRC_BITS 17
#define SRC_MASK ((1 << SRC_BITS) - 1)
#define T1_SCALE 256.0f
#define T1_INV_SCALE (1.0f / 256.0f)

static_assert(GCN_N < (1 << SRC_BITS), "src id must fit 17 bits");

using short8 = __attribute__((ext_vector_type(8))) short;
using f32x4  = __attribute__((ext_vector_type(4))) float;
using f32x2  = __attribute__((ext_vector_type(2))) float;

#if defined(__has_builtin)
#if __has_builtin(__builtin_amdgcn_cvt_pk_f32_fp8) && __has_builtin(__builtin_amdgcn_cvt_pk_fp8_f32)
#define HW_FP8 1
#endif
#endif

// ---------------- bf16 / fp8 helpers ----------------

__device__ __forceinline__ unsigned short f2bf(float f) {
    unsigned u = __float_as_uint(f);
    unsigned r = u + 0x7FFFu + ((u >> 16) & 1u);   // round to nearest even
    return (unsigned short)(r >> 16);
}
__device__ __forceinline__ float bf2f(unsigned short h) {
    return __uint_as_float(((unsigned)h) << 16);
}

__device__ __forceinline__ void fp8x4_to_f32(unsigned v, float* f) {
#ifdef HW_FP8
    f32x2 lo = __builtin_amdgcn_cvt_pk_f32_fp8((int)v, false);
    f32x2 hi = __builtin_amdgcn_cvt_pk_f32_fp8((int)v, true);
    f[0] = lo[0]; f[1] = lo[1]; f[2] = hi[0]; f[3] = hi[1];
#else
    #pragma unroll
    for (int j = 0; j < 4; j++) {
        __hip_fp8_e4m3 h;
        h.__x = (unsigned char)((v >> (8 * j)) & 0xFF);
        f[j] = (float)h;
    }
#endif
}

__device__ __forceinline__ unsigned f32x4_to_fp8(float f0, float f1, float f2, float f3) {
#ifdef HW_FP8
    int r = __builtin_amdgcn_cvt_pk_fp8_f32(f0, f1, 0, false);
    r = __builtin_amdgcn_cvt_pk_fp8_f32(f2, f3, r, true);
    return (unsigned)r;
#else
    unsigned r = 0;
    float ff[4] = {f0, f1, f2, f3};
    #pragma unroll
    for (int j = 0; j < 4; j++) {
        __hip_fp8_e4m3 h(ff[j]);
        r |= ((unsigned)h.__x) << (8 * j);
    }
    return r;
#endif
}

// ---------------- CSR build: atomic-free radix partition ----------------

__global__ __launch_bounds__(256) void hist_kernel(const int* __restrict__ dst,
                                                   int* __restrict__ hist, int E) {
    __shared__ int lh[NBKT];
    int tid = threadIdx.x;
    if (tid < NBKT) lh[tid] = 0;
    __syncthreads();
    int e0 = blockIdx.x * CHUNK;
    #pragma unroll
    for (int i = 0; i < CHUNK / 256; i++) {
        int e = e0 + tid + i * 256;
        if (e < E) atomicAdd(&lh[dst[e] >> NPB_SHIFT], 1);
    }
    __syncthreads();
    if (tid < NBKT) hist[(size_t)blockIdx.x * NBKT + tid] = lh[tid];
}

__global__ __launch_bounds__(64) void scan_cols_kernel(const int* __restrict__ hist,
                                                       int* __restrict__ offsT,
                                                       int* __restrict__ btot, int B) {
    int k = blockIdx.x;
    int lane = threadIdx.x;
    int running = 0;
    for (int b0 = 0; b0 < B; b0 += 64) {
        int b = b0 + lane;
        int v = (b < B) ? hist[(size_t)b * NBKT + k] : 0;
        int iv = v;
        #pragma unroll
        for (int d = 1; d < 64; d <<= 1) {
            int x = __shfl_up(iv, d, 64);
            if (lane >= d) iv += x;
        }
        if (b < B) offsT[(size_t)k * B + b] = running + iv - v;   // exclusive
        running += __shfl(iv, 63, 64);
    }
    if (lane == 0) btot[k] = running;
}

__global__ void bucket_base_kernel(const int* __restrict__ btot,
                                   int* __restrict__ bbase,
                                   int* __restrict__ rowptr, int n) {
    if (threadIdx.x == 0 && blockIdx.x == 0) {
        int run = 0;
        for (int i = 0; i < NBKT; i++) { bbase[i] = run; run += btot[i]; }
        bbase[NBKT] = run;
        rowptr[n] = run;
    }
}

__global__ __launch_bounds__(256) void partition_kernel(const int* __restrict__ src,
                                                        const int* __restrict__ dst,
                                                        const int* __restrict__ bbase,
                                                        const int* __restrict__ offsT,
                                                        int* __restrict__ epack,
                                                        int E, int B) {
    __shared__ int cur[NBKT];
    int blk = blockIdx.x, tid = threadIdx.x;
    if (tid < NBKT) cur[tid] = bbase[tid] + offsT[(size_t)tid * B + blk];
    __syncthreads();
    int e0 = blk * CHUNK;
    #pragma unroll
    for (int i = 0; i < CHUNK / 256; i++) {
        int e = e0 + tid + i * 256;
        if (e < E) {
            int d = dst[e];
            int s = src[e];
            int pos = atomicAdd(&cur[d >> NPB_SHIFT], 1);
            epack[pos] = ((d & (NPB - 1)) << SRC_BITS) | s;
        }
    }
}

// builds local CSR AND writes dis + xsp (fused xscale)
__global__ __launch_bounds__(512) void csr_build_kernel(const int* __restrict__ epack,
                                                        const int* __restrict__ bbase,
                                                        const float* __restrict__ x,
                                                        int* __restrict__ rowptr,
                                                        float* __restrict__ dis,
                                                        float* __restrict__ xsp,
                                                        int* __restrict__ csrc, int n) {
    __shared__ int lcount[NPB];
    __shared__ int lcur[NPB];
    __shared__ int wsums[8];
    int k = blockIdx.x, tid = threadIdx.x;
    int lane = tid & 63, wid = tid >> 6;
    int nodebase = k << NPB_SHIFT;
    int ebeg = bbase[k], eend = bbase[k + 1];

    lcount[tid] = 0;
    __syncthreads();
    for (int e = ebeg + tid; e < eend; e += 512)
        atomicAdd(&lcount[epack[e] >> SRC_BITS], 1);
    __syncthreads();

    int v = lcount[tid];
    int iv = v;
    #pragma unroll
    for (int d = 1; d < 64; d <<= 1) {
        int x2 = __shfl_up(iv, d, 64);
        if (lane >= d) iv += x2;
    }
    if (lane == 63) wsums[wid] = iv;
    __syncthreads();
    if (tid == 0) {
        int r = 0;
        #pragma unroll
        for (int w = 0; w < 8; w++) { int t = wsums[w]; wsums[w] = r; r += t; }
    }
    __syncthreads();
    int ex = wsums[wid] + iv - v;
    lcur[tid] = ex;
    int node = nodebase + tid;
    if (node < n) {
        rowptr[node] = ebeg + ex;
        float dd = rsqrtf((float)(v + 1));       // deg = indeg + self-loop
        dis[node] = dd;
        // fused xscale: xsp row = dd * x row (padded to 8)
        const float* xr = x + (size_t)node * 5;
        float4 a;
        a.x = xr[0] * dd; a.y = xr[1] * dd; a.z = xr[2] * dd; a.w = xr[3] * dd;
        float a4 = xr[4] * dd;
        ((float4*)(xsp + (size_t)node * 8))[0] = a;
        xsp[(size_t)node * 8 + 4] = a4;
        xsp[(size_t)node * 8 + 5] = 0.f;
        xsp[(size_t)node * 8 + 6] = 0.f;
        xsp[(size_t)node * 8 + 7] = 0.f;
    }
    __syncthreads();
    for (int e = ebeg + tid; e < eend; e += 512) {
        int p = epack[e];
        int pos = atomicAdd(&lcur[p >> SRC_BITS], 1);
        csrc[ebeg + pos] = p & SRC_MASK;
    }
}

// ---------------- layer-0 aggregation (5-dim) ----------------

__global__ __launch_bounds__(256) void aggx_kernel(const float* __restrict__ xsp,
                                                   const float* __restrict__ dis,
                                                   const int* __restrict__ rowptr,
                                                   const int* __restrict__ csrc,
                                                   float* __restrict__ a0p, int n) {
    int i = blockIdx.x * 256 + threadIdx.x;
    if (i >= n) return;
    float4 acc = ((const float4*)(xsp + (size_t)i * 8))[0];
    float acc4 = xsp[(size_t)i * 8 + 4];
    int r0 = rowptr[i], r1 = rowptr[i + 1];
    int e = r0;
    for (; e + 3 < r1; e += 4) {
        int s0 = csrc[e], s1 = csrc[e + 1], s2 = csrc[e + 2], s3 = csrc[e + 3];
        float4 v0 = ((const float4*)(xsp + (size_t)s0 * 8))[0];
        float a40 = xsp[(size_t)s0 * 8 + 4];
        float4 v1 = ((const float4*)(xsp + (size_t)s1 * 8))[0];
        float a41 = xsp[(size_t)s1 * 8 + 4];
        float4 v2 = ((const float4*)(xsp + (size_t)s2 * 8))[0];
        float a42 = xsp[(size_t)s2 * 8 + 4];
        float4 v3 = ((const float4*)(xsp + (size_t)s3 * 8))[0];
        float a43 = xsp[(size_t)s3 * 8 + 4];
        acc.x += (v0.x + v1.x) + (v2.x + v3.x);
        acc.y += (v0.y + v1.y) + (v2.y + v3.y);
        acc.z += (v0.z + v1.z) + (v2.z + v3.z);
        acc.w += (v0.w + v1.w) + (v2.w + v3.w);
        acc4  += (a40 + a41) + (a42 + a43);
    }
    for (; e < r1; e++) {
        int s = csrc[e];
        float4 v = ((const float4*)(xsp + (size_t)s * 8))[0];
        acc.x += v.x; acc.y += v.y; acc.z += v.z; acc.w += v.w;
        acc4 += xsp[(size_t)s * 8 + 4];
    }
    float di = dis[i];
    acc.x *= di; acc.y *= di; acc.z *= di; acc.w *= di; acc4 *= di;
    ((float4*)(a0p + (size_t)i * 8))[0] = acc;
    a0p[(size_t)i * 8 + 4] = acc4;
}

// ---------------- prep: w2l, c2, W1^T -> bf16 ----------------

__global__ __launch_bounds__(256) void w2l_kernel(const float* __restrict__ W2,
                                                  const float* __restrict__ b2,
                                                  const float* __restrict__ lw,
                                                  float* __restrict__ w2l,
                                                  float* __restrict__ c2) {
    __shared__ float slw[128];
    int tid = threadIdx.x;
    if (tid < 128) slw[tid] = lw[tid];
    __syncthreads();
    if (tid < 128) {
        float s = 0.f;
        #pragma unroll 8
        for (int j = 0; j < 128; j++) s = fmaf(W2[tid * 128 + j], slw[j], s);
        w2l[tid] = s;
    } else if (tid == 128) {
        float s = 0.f;
        for (int j = 0; j < 128; j++) s = fmaf(b2[j], slw[j], s);
        c2[0] = s;
    }
}

// w1t[col][k] = bf16(W1[k][col])
__global__ __launch_bounds__(256) void w1cvt_kernel(const float* __restrict__ W1,
                                                    unsigned short* __restrict__ w1t) {
    int idx = blockIdx.x * 256 + threadIdx.x;   // 0..16383
    int col = idx >> 7, k = idx & 127;
    w1t[idx] = f2bf(W1[k * 128 + col]);
}

// ------- fused mm (MFMA): t1 = fp8( 256 * dis ⊙ (relu(a0@W0 + b0) @ W1) ) -------

__global__ __launch_bounds__(256) void mmfused_kernel(const float* __restrict__ a0p,
                                                      const float* __restrict__ W0,
                                                      const float* __restrict__ b0,
                                                      const unsigned short* __restrict__ w1t,
                                                      const float* __restrict__ dis,
                                                      unsigned* __restrict__ t1f8, int n) {
    __shared__ __align__(16) unsigned short sA[128 * 128];   // 32 KB h1 / reused for out
    __shared__ __align__(16) unsigned short sBT[128 * 128];  // 32 KB W1^T
    __shared__ __align__(16) float4 sA0[256];                // 4 KB a0p rows
    __shared__ float sDis[128];
    char* sAb = (char*)sA;
    char* sBb = (char*)sBT;
    int tid = threadIdx.x;
    int rowBase = blockIdx.x * 128;

    // stage a0p rows + dis
    {
        int rowL = tid >> 1, q = tid & 1;
        int gr = rowBase + rowL;
        float4 v = make_float4(0.f, 0.f, 0.f, 0.f);
        if (gr < n) v = ((const float4*)a0p)[(size_t)gr * 2 + q];
        sA0[tid] = v;
        if (tid < 128) {
            int g2 = rowBase + tid;
            sDis[tid] = (g2 < n) ? dis[g2] : 0.f;
        }
    }
    // stage w1t (bf16, pre-transposed) -> sBT swizzled, ds_write_b128
    #pragma unroll
    for (int it = 0; it < 8; it++) {
        int idx = tid + it * 256;           // uint4 index, 0..2047
        int col = idx >> 4, c = idx & 15;   // c: 16B chunk = 8 k-values
        uint4 v = ((const uint4*)w1t)[idx];
        int byteoff = (col * 256 + c * 16) ^ ((col & 7) << 4);
        *(uint4*)(sBb + byteoff) = v;
    }
    __syncthreads();

    // h1 = relu(a0 @ W0 + b0) -> sA bf16, swizzled. thread: 4 fixed cols x 16 rows.
    {
        int cq = tid & 31;          // col quad: cols cq*4..cq*4+3
        int rg = tid >> 5;          // row group 0..7
        float4 w0q[5];
        #pragma unroll
        for (int j = 0; j < 5; j++) w0q[j] = *((const float4*)(W0 + j * 128 + cq * 4));
        float4 b0q = *((const float4*)(b0 + cq * 4));
        const float* sA0f = (const float*)sA0;
        #pragma unroll
        for (int ri = 0; ri < 16; ri++) {
            int row = rg + ri * 8;
            const float* ar = sA0f + row * 8;
            float4 h = b0q;
            #pragma unroll
            for (int j = 0; j < 5; j++) {
                float aj = ar[j];
                h.x = fmaf(aj, w0q[j].x, h.x);
                h.y = fmaf(aj, w0q[j].y, h.y);
                h.z = fmaf(aj, w0q[j].z, h.z);
                h.w = fmaf(aj, w0q[j].w, h.w);
            }
            h.x = fmaxf(h.x, 0.f); h.y = fmaxf(h.y, 0.f);
            h.z = fmaxf(h.z, 0.f); h.w = fmaxf(h.w, 0.f);
            uint2 p;
            p.x = (unsigned)f2bf(h.x) | ((unsigned)f2bf(h.y) << 16);
            p.y = (unsigned)f2bf(h.z) | ((unsigned)f2bf(h.w) << 16);
            int byteoff = (row * 256 + cq * 8) ^ ((row & 7) << 4);
            *(uint2*)(sAb + byteoff) = p;
        }
    }
    __syncthreads();

    // MFMA: wave w owns rows w*32 .. w*32+31
    int wave = tid >> 6, l = tid & 63;
    int lr = l & 15, lg = l >> 4;
    int rb = wave * 32;

    short8 afr[2][4];
    #pragma unroll
    for (int rt = 0; rt < 2; rt++) {
        int row = rb + rt * 16 + lr;
        #pragma unroll
        for (int ks = 0; ks < 4; ks++) {
            int byteoff = (row * 256 + ks * 64 + lg * 16) ^ ((row & 7) << 4);
            afr[rt][ks] = *(const short8*)(sAb + byteoff);
        }
    }
    f32x4 acc[2][8];
    #pragma unroll
    for (int rt = 0; rt < 2; rt++)
        #pragma unroll
        for (int ct = 0; ct < 8; ct++)
            acc[rt][ct] = (f32x4){0.f, 0.f, 0.f, 0.f};

    #pragma unroll
    for (int ct = 0; ct < 8; ct++) {
        int col = ct * 16 + lr;
        short8 bfr[4];
        #pragma unroll
        for (int ks = 0; ks < 4; ks++) {
            int byteoff = (col * 256 + ks * 64 + lg * 16) ^ ((col & 7) << 4);
            bfr[ks] = *(const short8*)(sBb + byteoff);
        }
        #pragma unroll
        for (int rt = 0; rt < 2; rt++) {
            #pragma unroll
            for (int ks = 0; ks < 4; ks++) {
                acc[rt][ct] = __builtin_amdgcn_mfma_f32_16x16x32_bf16(
                    afr[rt][ks], bfr[ks], acc[rt][ct], 0, 0, 0);
            }
        }
    }

    // epilogue: dis*256-scale, bf16, write back into own sA rows (swizzled)
    #pragma unroll
    for (int rt = 0; rt < 2; rt++) {
        #pragma unroll
        for (int i = 0; i < 4; i++) {
            int rowL = rb + rt * 16 + lg * 4 + i;
            float dsc = sDis[rowL] * T1_SCALE;
            #pragma unroll
            for (int ct = 0; ct < 8; ct++) {
                int col = ct * 16 + lr;
                int byteoff = (rowL * 256 + col * 2) ^ ((rowL & 7) << 4);
                *(unsigned short*)(sAb + byteoff) = f2bf(acc[rt][ct][i] * dsc);
            }
        }
    }
    __syncthreads();

    // copy-out with bf16 -> fp8 conversion
    #pragma unroll
    for (int it = 0; it < 8; it++) {
        int flat = tid + it * 256;
        int rowL = flat >> 4, c16 = flat & 15;
        int gr = rowBase + rowL;
        if (gr < n) {
            int byteoff = (rowL * 256 + c16 * 16) ^ ((rowL & 7) << 4);
            uint4 v = *(const uint4*)(sAb + byteoff);
            float f0 = __uint_as_float(v.x << 16), f1 = __uint_as_float(v.x & 0xFFFF0000u);
            float f2 = __uint_as_float(v.y << 16), f3 = __uint_as_float(v.y & 0xFFFF0000u);
            float f4 = __uint_as_float(v.z << 16), f5 = __uint_as_float(v.z & 0xFFFF0000u);
            float f6 = __uint_as_float(v.w << 16), f7 = __uint_as_float(v.w & 0xFFFF0000u);
            uint2 p;
            p.x = f32x4_to_fp8(f0, f1, f2, f3);
            p.y = f32x4_to_fp8(f4, f5, f6, f7);
            ((uint2*)t1f8)[(size_t)gr * 16 + c16] = p;
        }
    }
}

// --------- layer-1 aggregation (fp8 gather, 16 lanes/node) + layer-2 dot ---------

__global__ __launch_bounds__(256) void agg1_kernel(const unsigned* __restrict__ t1f8,
                                                   const float* __restrict__ dis,
                                                   const int* __restrict__ rowptr,
                                                   const int* __restrict__ csrc,
                                                   const float* __restrict__ b1,
                                                   const float* __restrict__ w2l,
                                                   float* __restrict__ z, int n) {
    int group = threadIdx.x >> 4, lane = threadIdx.x & 15;
    int i = blockIdx.x * 16 + group;
    if (i >= n) return;
    const uint2* t2 = (const uint2*)t1f8;        // 16 x uint2 per row (8 fp8 each)
    float f[8];
    uint2 sv = t2[(size_t)i * 16 + lane];
    fp8x4_to_f32(sv.x, f);
    fp8x4_to_f32(sv.y, f + 4);
    float acc[8];
    #pragma unroll
    for (int j = 0; j < 8; j++) acc[j] = f[j];
    int r0 = rowptr[i], r1 = rowptr[i + 1];
    int e = r0;
    for (; e + 7 < r1; e += 8) {
        uint2 vv[8];
        #pragma unroll
        for (int u = 0; u < 8; u++) vv[u] = t2[(size_t)csrc[e + u] * 16 + lane];
        #pragma unroll
        for (int u = 0; u < 8; u++) {
            fp8x4_to_f32(vv[u].x, f);
            fp8x4_to_f32(vv[u].y, f + 4);
            #pragma unroll
            for (int j = 0; j < 8; j++) acc[j] += f[j];
        }
    }
    for (; e < r1; e++) {
        uint2 v = t2[(size_t)csrc[e] * 16 + lane];
        fp8x4_to_f32(v.x, f);
        fp8x4_to_f32(v.y, f + 4);
        #pragma unroll
        for (int j = 0; j < 8; j++) acc[j] += f[j];
    }
    float di = dis[i];
    float dis_s = di * T1_INV_SCALE;
    float4 b4a = ((const float4*)b1)[lane * 2];
    float4 b4b = ((const float4*)b1)[lane * 2 + 1];
    float4 w4a = ((const float4*)w2l)[lane * 2];
    float4 w4b = ((const float4*)w2l)[lane * 2 + 1];
    float bb[8] = {b4a.x, b4a.y, b4a.z, b4a.w, b4b.x, b4b.y, b4b.z, b4b.w};
    float ww[8] = {w4a.x, w4a.y, w4a.z, w4a.w, w4b.x, w4b.y, w4b.z, w4b.w};
    float d = 0.f;
    #pragma unroll
    for (int j = 0; j < 8; j++) {
        float c = fmaxf(fmaf(dis_s, acc[j], bb[j]), 0.f);
        d = fmaf(c, ww[j], d);
    }
    #pragma unroll
    for (int o = 8; o > 0; o >>= 1) d += __shfl_down(d, o, 16);
    if (lane == 0) z[i] = di * d;
}

// ---------------- layer-2 scalar aggregation fused with pooling ----------------

__global__ __launch_bounds__(256) void aggz_pool_kernel(const float* __restrict__ z,
                                                        const float* __restrict__ dis,
                                                        const int* __restrict__ rowptr,
                                                        const int* __restrict__ csrc,
                                                        const int* __restrict__ batch,
                                                        float* __restrict__ gsum, int n) {
    __shared__ float lg[GCN_G];
    int tid = threadIdx.x;
    lg[tid] = 0.f;
    __syncthreads();
    int i = blockIdx.x * 256 + tid;
    float ndv = 0.f;
    int g = 0;
    if (i < n) {
        float acc = z[i];
        int r0 = rowptr[i], r1 = rowptr[i + 1];
        int e = r0;
        for (; e + 3 < r1; e += 4) {
            acc += (z[csrc[e]] + z[csrc[e + 1]]) + (z[csrc[e + 2]] + z[csrc[e + 3]]);
        }
        for (; e < r1; e++) acc += z[csrc[e]];
        ndv = dis[i] * acc;
        g = batch[i];
    }
    int lane = tid & 63;
    int g0 = __shfl(g, 0, 64);
    bool uni = __all(g == g0);
    if (uni) {
        float s = ndv;
        #pragma unroll
        for (int o = 32; o > 0; o >>= 1) s += __shfl_down(s, o, 64);
        if (lane == 0 && s != 0.f) atomicAdd(&lg[g0], s);
    } else {
        if (ndv != 0.f) atomicAdd(&lg[g], ndv);
    }
    __syncthreads();
    float v = lg[tid];
    if (v != 0.f) atomicAdd(&gsum[tid], v);
}

// ---------------- pooling boundaries + final ----------------

__global__ __launch_bounds__(256) void boundary_kernel(const int* __restrict__ batch,
                                                       int* __restrict__ gstart, int n) {
    int i = blockIdx.x * 256 + threadIdx.x;
    if (i >= n) return;
    int b = batch[i];
    int pb = (i == 0) ? -1 : batch[i - 1];
    for (int g = pb + 1; g <= b; g++) gstart[g] = i;
    if (i == n - 1) {
        for (int g = b + 1; g <= GCN_G; g++) gstart[g] = n;
    }
}

__global__ __launch_bounds__(256) void final_kernel(const float* __restrict__ gsum,
                                                    const int* __restrict__ gstart,
                                                    const float* __restrict__ c2,
                                                    const float* __restrict__ lb,
                                                    float* __restrict__ out) {
    int g = threadIdx.x;
    float cnt = (float)max(gstart[g + 1] - gstart[g], 1);
    float v = gsum[g] / cnt + c2[0] + lb[0];
    out[g] = 1.f / (1.f + expf(-v));
}

// ---------------- launch ----------------

extern "C" void kernel_launch(void* const* d_in, const int* in_sizes, int n_in,
                              void* d_out, int out_size, void* d_ws, size_t ws_size,
                              hipStream_t stream) {
    const float* x   = (const float*)d_in[0];
    const int*   ei  = (const int*)d_in[1];
    const int*   bat = (const int*)d_in[2];
    const float* W0  = (const float*)d_in[3];
    const float* b0  = (const float*)d_in[4];
    const float* W1  = (const float*)d_in[5];
    const float* b1  = (const float*)d_in[6];
    const float* W2  = (const float*)d_in[7];
    const float* b2  = (const float*)d_in[8];
    const float* lw  = (const float*)d_in[9];
    const float* lb  = (const float*)d_in[10];
    float* out = (float*)d_out;

    const int N = GCN_N;
    const int E = in_sizes[1] / 2;
    const int B = (E + CHUNK - 1) / CHUNK;

    char* ws = (char*)d_ws;
    size_t off = 0;
    auto alloc = [&](size_t bytes) {
        size_t o = off;
        off += (bytes + 255) & ~(size_t)255;
        return o;
    };
    int*   hist    = (int*)(ws + alloc((size_t)B * NBKT * 4));
    int*   offsT   = (int*)(ws + alloc((size_t)NBKT * B * 4));
    int*   btot    = (int*)(ws + alloc((size_t)NBKT * 4));
    int*   bbase   = (int*)(ws + alloc((size_t)(NBKT + 1) * 4));
    int*   epack   = (int*)(ws + alloc((size_t)E * 4));
    int*   rowptr  = (int*)(ws + alloc((size_t)(N + 1) * 4));
    float* dis     = (float*)(ws + alloc((size_t)N * 4));
    int*   csrc    = (int*)(ws + alloc((size_t)E * 4));
    float* xsp     = (float*)(ws + alloc((size_t)N * 8 * 4));
    float* a0p     = (float*)(ws + alloc((size_t)N * 8 * 4));
    unsigned* t1f8 = (unsigned*)(ws + alloc((size_t)N * GCN_H));
    float* z       = (float*)(ws + alloc((size_t)N * 4));
    int*   gstart  = (int*)(ws + alloc((size_t)(GCN_G + 1) * 4));
    float* w2l     = (float*)(ws + alloc(128 * 4));
    float* c2      = (float*)(ws + alloc(4));
    unsigned short* w1t = (unsigned short*)(ws + alloc(128 * 128 * 2));
    float* gsum    = (float*)(ws + alloc(GCN_G * 4));

    const int* src = ei;
    const int* dst = ei + E;

    hipMemsetAsync(gsum, 0, GCN_G * 4, stream);

    hist_kernel<<<B, 256, 0, stream>>>(dst, hist, E);
    scan_cols_kernel<<<NBKT, 64, 0, stream>>>(hist, offsT, btot, B);
    bucket_base_kernel<<<1, 64, 0, stream>>>(btot, bbase, rowptr, N);
    partition_kernel<<<B, 256, 0, stream>>>(src, dst, bbase, offsT, epack, E, B);
    csr_build_kernel<<<NBKT, 512, 0, stream>>>(epack, bbase, x, rowptr, dis, xsp, csrc, N);
    boundary_kernel<<<(N + 255) / 256, 256, 0, stream>>>(bat, gstart, N);
    w2l_kernel<<<1, 256, 0, stream>>>(W2, b2, lw, w2l, c2);
    w1cvt_kernel<<<64, 256, 0, stream>>>(W1, w1t);

    aggx_kernel<<<(N + 255) / 256, 256, 0, stream>>>(xsp, dis, rowptr, csrc, a0p, N);
    mmfused_kernel<<<(N + 127) / 128, 256, 0, stream>>>(a0p, W0, b0, w1t, dis, t1f8, N);
    agg1_kernel<<<(N + 15) / 16, 256, 0, stream>>>(t1f8, dis, rowptr, csrc, b1, w2l, z, N);
    aggz_pool_kernel<<<(N + 255) / 256, 256, 0, stream>>>(z, dis, rowptr, csrc, bat, gsum, N);

    final_kernel<<<1, 256, 0, stream>>>(gsum, gstart, c2, lb, out);
}

// Round 9
// 149.592 us; speedup vs baseline: 6.6539x; 1.0159x over previous
//
#include <hip/hip_runtime.h>
#include <hip/hip_fp8.h>

#define GCN_N 100000
#define GCN_H 128
#define GCN_G 256
#define NPB_SHIFT 9                    // 512 nodes per bucket
#define NPB 512
#define NBKT 196                       // ceil(100000/512)
#define CHUNK 2048                     // edges per hist/partition block
#define SRC_BITS 17
#define SRC_MASK ((1 << SRC_BITS) - 1)
#define T1_SCALE 256.0f
#define T1_INV_SCALE (1.0f / 256.0f)
#define EBUF_CAP 10240                 // LDS staging for csr_build (avg 8192/bucket)

static_assert(GCN_N < (1 << SRC_BITS), "src id must fit 17 bits");

using short8 = __attribute__((ext_vector_type(8))) short;
using f32x4  = __attribute__((ext_vector_type(4))) float;
using f32x2  = __attribute__((ext_vector_type(2))) float;

#if defined(__has_builtin)
#if __has_builtin(__builtin_amdgcn_cvt_pk_f32_fp8) && __has_builtin(__builtin_amdgcn_cvt_pk_fp8_f32)
#define HW_FP8 1
#endif
#endif

// ---------------- bf16 / fp8 helpers ----------------

__device__ __forceinline__ unsigned short f2bf(float f) {
    unsigned u = __float_as_uint(f);
    unsigned r = u + 0x7FFFu + ((u >> 16) & 1u);   // round to nearest even
    return (unsigned short)(r >> 16);
}
__device__ __forceinline__ float bf2f(unsigned short h) {
    return __uint_as_float(((unsigned)h) << 16);
}

__device__ __forceinline__ void fp8x4_to_f32(unsigned v, float* f) {
#ifdef HW_FP8
    f32x2 lo = __builtin_amdgcn_cvt_pk_f32_fp8((int)v, false);
    f32x2 hi = __builtin_amdgcn_cvt_pk_f32_fp8((int)v, true);
    f[0] = lo[0]; f[1] = lo[1]; f[2] = hi[0]; f[3] = hi[1];
#else
    #pragma unroll
    for (int j = 0; j < 4; j++) {
        __hip_fp8_e4m3 h;
        h.__x = (unsigned char)((v >> (8 * j)) & 0xFF);
        f[j] = (float)h;
    }
#endif
}

__device__ __forceinline__ unsigned f32x4_to_fp8(float f0, float f1, float f2, float f3) {
#ifdef HW_FP8
    int r = __builtin_amdgcn_cvt_pk_fp8_f32(f0, f1, 0, false);
    r = __builtin_amdgcn_cvt_pk_fp8_f32(f2, f3, r, true);
    return (unsigned)r;
#else
    unsigned r = 0;
    float ff[4] = {f0, f1, f2, f3};
    #pragma unroll
    for (int j = 0; j < 4; j++) {
        __hip_fp8_e4m3 h(ff[j]);
        r |= ((unsigned)h.__x) << (8 * j);
    }
    return r;
#endif
}

// ---------------- CSR build: atomic-free radix partition ----------------

__global__ __launch_bounds__(256) void hist_kernel(const int* __restrict__ dst,
                                                   int* __restrict__ hist, int E) {
    __shared__ int lh[NBKT];
    int tid = threadIdx.x;
    if (tid < NBKT) lh[tid] = 0;
    __syncthreads();
    int e0 = blockIdx.x * CHUNK;
    #pragma unroll
    for (int i = 0; i < CHUNK / 256; i++) {
        int e = e0 + tid + i * 256;
        if (e < E) atomicAdd(&lh[dst[e] >> NPB_SHIFT], 1);
    }
    __syncthreads();
    if (tid < NBKT) hist[(size_t)blockIdx.x * NBKT + tid] = lh[tid];
}

__global__ __launch_bounds__(64) void scan_cols_kernel(const int* __restrict__ hist,
                                                       int* __restrict__ offsT,
                                                       int* __restrict__ btot, int B) {
    int k = blockIdx.x;
    int lane = threadIdx.x;
    int running = 0;
    for (int b0 = 0; b0 < B; b0 += 64) {
        int b = b0 + lane;
        int v = (b < B) ? hist[(size_t)b * NBKT + k] : 0;
        int iv = v;
        #pragma unroll
        for (int d = 1; d < 64; d <<= 1) {
            int x = __shfl_up(iv, d, 64);
            if (lane >= d) iv += x;
        }
        if (b < B) offsT[(size_t)k * B + b] = running + iv - v;   // exclusive
        running += __shfl(iv, 63, 64);
    }
    if (lane == 0) btot[k] = running;
}

// fused prep: blocks 0..63 = W1^T->bf16; block 64 = w2l+c2; block 65 = bucket_base
__global__ __launch_bounds__(256) void prep_kernel(const float* __restrict__ W1,
                                                   const float* __restrict__ W2,
                                                   const float* __restrict__ b2,
                                                   const float* __restrict__ lw,
                                                   const int* __restrict__ btot,
                                                   unsigned short* __restrict__ w1t,
                                                   float* __restrict__ w2l,
                                                   float* __restrict__ c2,
                                                   int* __restrict__ bbase,
                                                   int* __restrict__ rowptr, int n) {
    __shared__ float slw[128];
    int blk = blockIdx.x, tid = threadIdx.x;
    if (blk < 64) {
        int idx = blk * 256 + tid;                 // 0..16383
        int col = idx >> 7, k = idx & 127;
        w1t[idx] = f2bf(W1[k * 128 + col]);
    } else if (blk == 64) {
        if (tid < 128) slw[tid] = lw[tid];
        __syncthreads();
        if (tid < 128) {
            float s = 0.f;
            #pragma unroll 8
            for (int j = 0; j < 128; j++) s = fmaf(W2[tid * 128 + j], slw[j], s);
            w2l[tid] = s;
        } else if (tid == 128) {
            float s = 0.f;
            for (int j = 0; j < 128; j++) s = fmaf(b2[j], slw[j], s);
            c2[0] = s;
        }
    } else {
        if (tid == 0) {
            int run = 0;
            for (int i = 0; i < NBKT; i++) { bbase[i] = run; run += btot[i]; }
            bbase[NBKT] = run;
            rowptr[n] = run;
        }
    }
}

__global__ __launch_bounds__(256) void partition_kernel(const int* __restrict__ src,
                                                        const int* __restrict__ dst,
                                                        const int* __restrict__ bbase,
                                                        const int* __restrict__ offsT,
                                                        int* __restrict__ epack,
                                                        int E, int B) {
    __shared__ int cur[NBKT];
    int blk = blockIdx.x, tid = threadIdx.x;
    if (tid < NBKT) cur[tid] = bbase[tid] + offsT[(size_t)tid * B + blk];
    __syncthreads();
    int e0 = blk * CHUNK;
    #pragma unroll
    for (int i = 0; i < CHUNK / 256; i++) {
        int e = e0 + tid + i * 256;
        if (e < E) {
            int d = dst[e];
            int s = src[e];
            int pos = atomicAdd(&cur[d >> NPB_SHIFT], 1);
            epack[pos] = ((d & (NPB - 1)) << SRC_BITS) | s;
        }
    }
}

// builds local CSR AND writes dis + xsp (fused xscale); LDS-stages its epack slice
__global__ __launch_bounds__(512) void csr_build_kernel(const int* __restrict__ epack,
                                                        const int* __restrict__ bbase,
                                                        const float* __restrict__ x,
                                                        int* __restrict__ rowptr,
                                                        float* __restrict__ dis,
                                                        float* __restrict__ xsp,
                                                        int* __restrict__ csrc, int n) {
    __shared__ int ebuf[EBUF_CAP];              // 40 KB
    __shared__ int lcount[NPB];
    __shared__ int lcur[NPB];
    __shared__ int wsums[8];
    int k = blockIdx.x, tid = threadIdx.x;
    int lane = tid & 63, wid = tid >> 6;
    int nodebase = k << NPB_SHIFT;
    int ebeg = bbase[k], eend = bbase[k + 1];
    bool fits = (eend - ebeg) <= EBUF_CAP;

    lcount[tid] = 0;
    __syncthreads();
    for (int e = ebeg + tid; e < eend; e += 512) {
        int p = epack[e];
        if (fits) ebuf[e - ebeg] = p;
        atomicAdd(&lcount[p >> SRC_BITS], 1);
    }
    __syncthreads();

    int v = lcount[tid];
    int iv = v;
    #pragma unroll
    for (int d = 1; d < 64; d <<= 1) {
        int x2 = __shfl_up(iv, d, 64);
        if (lane >= d) iv += x2;
    }
    if (lane == 63) wsums[wid] = iv;
    __syncthreads();
    if (tid == 0) {
        int r = 0;
        #pragma unroll
        for (int w = 0; w < 8; w++) { int t = wsums[w]; wsums[w] = r; r += t; }
    }
    __syncthreads();
    int ex = wsums[wid] + iv - v;
    lcur[tid] = ex;
    int node = nodebase + tid;
    if (node < n) {
        rowptr[node] = ebeg + ex;
        float dd = rsqrtf((float)(v + 1));       // deg = indeg + self-loop
        dis[node] = dd;
        const float* xr = x + (size_t)node * 5;
        float4 a;
        a.x = xr[0] * dd; a.y = xr[1] * dd; a.z = xr[2] * dd; a.w = xr[3] * dd;
        float a4 = xr[4] * dd;
        ((float4*)(xsp + (size_t)node * 8))[0] = a;
        xsp[(size_t)node * 8 + 4] = a4;
        xsp[(size_t)node * 8 + 5] = 0.f;
        xsp[(size_t)node * 8 + 6] = 0.f;
        xsp[(size_t)node * 8 + 7] = 0.f;
    }
    __syncthreads();
    for (int e = ebeg + tid; e < eend; e += 512) {
        int p = fits ? ebuf[e - ebeg] : epack[e];
        int pos = atomicAdd(&lcur[p >> SRC_BITS], 1);
        csrc[ebeg + pos] = p & SRC_MASK;
    }
}

// ---------------- layer-0 aggregation (5-dim, 8-deep prefetch) ----------------

__global__ __launch_bounds__(256) void aggx_kernel(const float* __restrict__ xsp,
                                                   const float* __restrict__ dis,
                                                   const int* __restrict__ rowptr,
                                                   const int* __restrict__ csrc,
                                                   float* __restrict__ a0p, int n) {
    int i = blockIdx.x * 256 + threadIdx.x;
    if (i >= n) return;
    float4 acc = ((const float4*)(xsp + (size_t)i * 8))[0];
    float acc4 = xsp[(size_t)i * 8 + 4];
    int r0 = rowptr[i], r1 = rowptr[i + 1];
    int e = r0;
    for (; e + 7 < r1; e += 8) {
        int ss[8];
        #pragma unroll
        for (int u = 0; u < 8; u++) ss[u] = csrc[e + u];
        float4 v[8]; float a4[8];
        #pragma unroll
        for (int u = 0; u < 8; u++) {
            v[u] = ((const float4*)(xsp + (size_t)ss[u] * 8))[0];
            a4[u] = xsp[(size_t)ss[u] * 8 + 4];
        }
        #pragma unroll
        for (int u = 0; u < 8; u++) {
            acc.x += v[u].x; acc.y += v[u].y; acc.z += v[u].z; acc.w += v[u].w;
            acc4 += a4[u];
        }
    }
    for (; e < r1; e++) {
        int s = csrc[e];
        float4 v = ((const float4*)(xsp + (size_t)s * 8))[0];
        acc.x += v.x; acc.y += v.y; acc.z += v.z; acc.w += v.w;
        acc4 += xsp[(size_t)s * 8 + 4];
    }
    float di = dis[i];
    acc.x *= di; acc.y *= di; acc.z *= di; acc.w *= di; acc4 *= di;
    ((float4*)(a0p + (size_t)i * 8))[0] = acc;
    a0p[(size_t)i * 8 + 4] = acc4;
}

// ------- fused mm (MFMA): t1 = fp8( 256 * dis ⊙ (relu(a0@W0 + b0) @ W1) ) -------

__global__ __launch_bounds__(256) void mmfused_kernel(const float* __restrict__ a0p,
                                                      const float* __restrict__ W0,
                                                      const float* __restrict__ b0,
                                                      const unsigned short* __restrict__ w1t,
                                                      const float* __restrict__ dis,
                                                      unsigned* __restrict__ t1f8, int n) {
    __shared__ __align__(16) unsigned short sA[128 * 128];   // 32 KB h1 / reused for out
    __shared__ __align__(16) unsigned short sBT[128 * 128];  // 32 KB W1^T
    __shared__ __align__(16) float4 sA0[256];                // 4 KB a0p rows
    __shared__ float sDis[128];
    char* sAb = (char*)sA;
    char* sBb = (char*)sBT;
    int tid = threadIdx.x;
    int rowBase = blockIdx.x * 128;

    {
        int rowL = tid >> 1, q = tid & 1;
        int gr = rowBase + rowL;
        float4 v = make_float4(0.f, 0.f, 0.f, 0.f);
        if (gr < n) v = ((const float4*)a0p)[(size_t)gr * 2 + q];
        sA0[tid] = v;
        if (tid < 128) {
            int g2 = rowBase + tid;
            sDis[tid] = (g2 < n) ? dis[g2] : 0.f;
        }
    }
    #pragma unroll
    for (int it = 0; it < 8; it++) {
        int idx = tid + it * 256;           // uint4 index, 0..2047
        int col = idx >> 4, c = idx & 15;   // c: 16B chunk = 8 k-values
        uint4 v = ((const uint4*)w1t)[idx];
        int byteoff = (col * 256 + c * 16) ^ ((col & 7) << 4);
        *(uint4*)(sBb + byteoff) = v;
    }
    __syncthreads();

    {
        int cq = tid & 31;          // col quad: cols cq*4..cq*4+3
        int rg = tid >> 5;          // row group 0..7
        float4 w0q[5];
        #pragma unroll
        for (int j = 0; j < 5; j++) w0q[j] = *((const float4*)(W0 + j * 128 + cq * 4));
        float4 b0q = *((const float4*)(b0 + cq * 4));
        const float* sA0f = (const float*)sA0;
        #pragma unroll
        for (int ri = 0; ri < 16; ri++) {
            int row = rg + ri * 8;
            const float* ar = sA0f + row * 8;
            float4 h = b0q;
            #pragma unroll
            for (int j = 0; j < 5; j++) {
                float aj = ar[j];
                h.x = fmaf(aj, w0q[j].x, h.x);
                h.y = fmaf(aj, w0q[j].y, h.y);
                h.z = fmaf(aj, w0q[j].z, h.z);
                h.w = fmaf(aj, w0q[j].w, h.w);
            }
            h.x = fmaxf(h.x, 0.f); h.y = fmaxf(h.y, 0.f);
            h.z = fmaxf(h.z, 0.f); h.w = fmaxf(h.w, 0.f);
            uint2 p;
            p.x = (unsigned)f2bf(h.x) | ((unsigned)f2bf(h.y) << 16);
            p.y = (unsigned)f2bf(h.z) | ((unsigned)f2bf(h.w) << 16);
            int byteoff = (row * 256 + cq * 8) ^ ((row & 7) << 4);
            *(uint2*)(sAb + byteoff) = p;
        }
    }
    __syncthreads();

    int wave = tid >> 6, l = tid & 63;
    int lr = l & 15, lg = l >> 4;
    int rb = wave * 32;

    short8 afr[2][4];
    #pragma unroll
    for (int rt = 0; rt < 2; rt++) {
        int row = rb + rt * 16 + lr;
        #pragma unroll
        for (int ks = 0; ks < 4; ks++) {
            int byteoff = (row * 256 + ks * 64 + lg * 16) ^ ((row & 7) << 4);
            afr[rt][ks] = *(const short8*)(sAb + byteoff);
        }
    }
    f32x4 acc[2][8];
    #pragma unroll
    for (int rt = 0; rt < 2; rt++)
        #pragma unroll
        for (int ct = 0; ct < 8; ct++)
            acc[rt][ct] = (f32x4){0.f, 0.f, 0.f, 0.f};

    #pragma unroll
    for (int ct = 0; ct < 8; ct++) {
        int col = ct * 16 + lr;
        short8 bfr[4];
        #pragma unroll
        for (int ks = 0; ks < 4; ks++) {
            int byteoff = (col * 256 + ks * 64 + lg * 16) ^ ((col & 7) << 4);
            bfr[ks] = *(const short8*)(sBb + byteoff);
        }
        #pragma unroll
        for (int rt = 0; rt < 2; rt++) {
            #pragma unroll
            for (int ks = 0; ks < 4; ks++) {
                acc[rt][ct] = __builtin_amdgcn_mfma_f32_16x16x32_bf16(
                    afr[rt][ks], bfr[ks], acc[rt][ct], 0, 0, 0);
            }
        }
    }

    #pragma unroll
    for (int rt = 0; rt < 2; rt++) {
        #pragma unroll
        for (int i = 0; i < 4; i++) {
            int rowL = rb + rt * 16 + lg * 4 + i;
            float dsc = sDis[rowL] * T1_SCALE;
            #pragma unroll
            for (int ct = 0; ct < 8; ct++) {
                int col = ct * 16 + lr;
                int byteoff = (rowL * 256 + col * 2) ^ ((rowL & 7) << 4);
                *(unsigned short*)(sAb + byteoff) = f2bf(acc[rt][ct][i] * dsc);
            }
        }
    }
    __syncthreads();

    #pragma unroll
    for (int it = 0; it < 8; it++) {
        int flat = tid + it * 256;
        int rowL = flat >> 4, c16 = flat & 15;
        int gr = rowBase + rowL;
        if (gr < n) {
            int byteoff = (rowL * 256 + c16 * 16) ^ ((rowL & 7) << 4);
            uint4 v = *(const uint4*)(sAb + byteoff);
            float f0 = __uint_as_float(v.x << 16), f1 = __uint_as_float(v.x & 0xFFFF0000u);
            float f2 = __uint_as_float(v.y << 16), f3 = __uint_as_float(v.y & 0xFFFF0000u);
            float f4 = __uint_as_float(v.z << 16), f5 = __uint_as_float(v.z & 0xFFFF0000u);
            float f6 = __uint_as_float(v.w << 16), f7 = __uint_as_float(v.w & 0xFFFF0000u);
            uint2 p;
            p.x = f32x4_to_fp8(f0, f1, f2, f3);
            p.y = f32x4_to_fp8(f4, f5, f6, f7);
            ((uint2*)t1f8)[(size_t)gr * 16 + c16] = p;
        }
    }
}

// --------- layer-1 aggregation (fp8, shuffle-batched 16-deep gather) + layer-2 dot ---------

__global__ __launch_bounds__(256) void agg1_kernel(const unsigned* __restrict__ t1f8,
                                                   const float* __restrict__ dis,
                                                   const int* __restrict__ rowptr,
                                                   const int* __restrict__ csrc,
                                                   const float* __restrict__ b1,
                                                   const float* __restrict__ w2l,
                                                   float* __restrict__ z, int n) {
    int group = threadIdx.x >> 4, lane = threadIdx.x & 15;
    int i = blockIdx.x * 16 + group;
    if (i >= n) return;
    const uint2* t2 = (const uint2*)t1f8;        // 16 x uint2 per row (8 fp8 each)
    float f[8], acc[8];
    uint2 sv = t2[(size_t)i * 16 + lane];
    fp8x4_to_f32(sv.x, f);
    fp8x4_to_f32(sv.y, f + 4);
    #pragma unroll
    for (int j = 0; j < 8; j++) acc[j] = f[j];
    int r0 = rowptr[i], r1 = rowptr[i + 1];
    for (int e = r0; e < r1; e += 16) {
        int cnt = r1 - e; if (cnt > 16) cnt = 16;   // uniform within group
        int idx = e + lane;
        int si = (idx < r1) ? csrc[idx] : 0;        // coalesced index load
        uint2 vv[16];
        #pragma unroll
        for (int u = 0; u < 16; u++) {
            if (u < cnt) {
                int s = __shfl(si, u, 16);
                vv[u] = t2[(size_t)s * 16 + lane];  // 16 independent gathers in flight
            }
        }
        #pragma unroll
        for (int u = 0; u < 16; u++) {
            if (u < cnt) {
                fp8x4_to_f32(vv[u].x, f);
                fp8x4_to_f32(vv[u].y, f + 4);
                #pragma unroll
                for (int j = 0; j < 8; j++) acc[j] += f[j];
            }
        }
    }
    float di = dis[i];
    float dis_s = di * T1_INV_SCALE;
    float4 b4a = ((const float4*)b1)[lane * 2];
    float4 b4b = ((const float4*)b1)[lane * 2 + 1];
    float4 w4a = ((const float4*)w2l)[lane * 2];
    float4 w4b = ((const float4*)w2l)[lane * 2 + 1];
    float bb[8] = {b4a.x, b4a.y, b4a.z, b4a.w, b4b.x, b4b.y, b4b.z, b4b.w};
    float ww[8] = {w4a.x, w4a.y, w4a.z, w4a.w, w4b.x, w4b.y, w4b.z, w4b.w};
    float d = 0.f;
    #pragma unroll
    for (int j = 0; j < 8; j++) {
        float c = fmaxf(fmaf(dis_s, acc[j], bb[j]), 0.f);
        d = fmaf(c, ww[j], d);
    }
    #pragma unroll
    for (int o = 8; o > 0; o >>= 1) d += __shfl_down(d, o, 16);
    if (lane == 0) z[i] = di * d;
}

// ------- layer-2 scalar aggregation fused with pooling (sums AND counts) -------

__global__ __launch_bounds__(256) void aggz_pool_kernel(const float* __restrict__ z,
                                                        const float* __restrict__ dis,
                                                        const int* __restrict__ rowptr,
                                                        const int* __restrict__ csrc,
                                                        const int* __restrict__ batch,
                                                        float* __restrict__ gsum,
                                                        int* __restrict__ gcnt, int n) {
    __shared__ float lg[GCN_G];
    __shared__ int lc[GCN_G];
    int tid = threadIdx.x;
    lg[tid] = 0.f;
    lc[tid] = 0;
    __syncthreads();
    int i = blockIdx.x * 256 + tid;
    bool valid = i < n;
    float ndv = 0.f;
    int g = 0;
    if (valid) {
        float acc = z[i];
        int r0 = rowptr[i], r1 = rowptr[i + 1];
        int e = r0;
        for (; e + 7 < r1; e += 8) {
            int ss[8];
            #pragma unroll
            for (int u = 0; u < 8; u++) ss[u] = csrc[e + u];
            float zv[8];
            #pragma unroll
            for (int u = 0; u < 8; u++) zv[u] = z[ss[u]];
            #pragma unroll
            for (int u = 0; u < 8; u++) acc += zv[u];
        }
        for (; e < r1; e++) acc += z[csrc[e]];
        ndv = dis[i] * acc;
        g = batch[i];
    }
    int lane = tid & 63;
    int g0 = __shfl(g, 0, 64);
    bool uni = __all(g == g0) && __all(valid);
    if (uni) {
        float s = ndv;
        #pragma unroll
        for (int o = 32; o > 0; o >>= 1) s += __shfl_down(s, o, 64);
        if (lane == 0) {
            atomicAdd(&lg[g0], s);
            atomicAdd(&lc[g0], 64);
        }
    } else if (valid) {
        atomicAdd(&lg[g], ndv);
        atomicAdd(&lc[g], 1);
    }
    __syncthreads();
    float v = lg[tid];
    int c = lc[tid];
    if (v != 0.f) atomicAdd(&gsum[tid], v);
    if (c != 0) atomicAdd(&gcnt[tid], c);
}

// ---------------- final ----------------

__global__ __launch_bounds__(256) void final_kernel(const float* __restrict__ gsum,
                                                    const int* __restrict__ gcnt,
                                                    const float* __restrict__ c2,
                                                    const float* __restrict__ lb,
                                                    float* __restrict__ out) {
    int g = threadIdx.x;
    float cnt = (float)max(gcnt[g], 1);
    float v = gsum[g] / cnt + c2[0] + lb[0];
    out[g] = 1.f / (1.f + expf(-v));
}

// ---------------- launch ----------------

extern "C" void kernel_launch(void* const* d_in, const int* in_sizes, int n_in,
                              void* d_out, int out_size, void* d_ws, size_t ws_size,
                              hipStream_t stream) {
    const float* x   = (const float*)d_in[0];
    const int*   ei  = (const int*)d_in[1];
    const int*   bat = (const int*)d_in[2];
    const float* W0  = (const float*)d_in[3];
    const float* b0  = (const float*)d_in[4];
    const float* W1  = (const float*)d_in[5];
    const float* b1  = (const float*)d_in[6];
    const float* W2  = (const float*)d_in[7];
    const float* b2  = (const float*)d_in[8];
    const float* lw  = (const float*)d_in[9];
    const float* lb  = (const float*)d_in[10];
    float* out = (float*)d_out;

    const int N = GCN_N;
    const int E = in_sizes[1] / 2;
    const int B = (E + CHUNK - 1) / CHUNK;

    char* ws = (char*)d_ws;
    size_t off = 0;
    auto alloc = [&](size_t bytes) {
        size_t o = off;
        off += (bytes + 255) & ~(size_t)255;
        return o;
    };
    int*   hist    = (int*)(ws + alloc((size_t)B * NBKT * 4));
    int*   offsT   = (int*)(ws + alloc((size_t)NBKT * B * 4));
    int*   btot    = (int*)(ws + alloc((size_t)NBKT * 4));
    int*   bbase   = (int*)(ws + alloc((size_t)(NBKT + 1) * 4));
    int*   epack   = (int*)(ws + alloc((size_t)E * 4));
    int*   rowptr  = (int*)(ws + alloc((size_t)(N + 1) * 4));
    float* dis     = (float*)(ws + alloc((size_t)N * 4));
    int*   csrc    = (int*)(ws + alloc((size_t)E * 4));
    float* xsp     = (float*)(ws + alloc((size_t)N * 8 * 4));
    float* a0p     = (float*)(ws + alloc((size_t)N * 8 * 4));
    unsigned* t1f8 = (unsigned*)(ws + alloc((size_t)N * GCN_H));
    float* z       = (float*)(ws + alloc((size_t)N * 4));
    float* w2l     = (float*)(ws + alloc(128 * 4));
    float* c2      = (float*)(ws + alloc(4));
    unsigned short* w1t = (unsigned short*)(ws + alloc(128 * 128 * 2));
    float* gsum    = (float*)(ws + alloc(GCN_G * 4));   // contiguous with gcnt
    int*   gcnt    = (int*)(ws + alloc(GCN_G * 4));

    const int* src = ei;
    const int* dst = ei + E;

    hipMemsetAsync(gsum, 0, GCN_G * 4 * 2, stream);     // gsum + gcnt

    hist_kernel<<<B, 256, 0, stream>>>(dst, hist, E);
    scan_cols_kernel<<<NBKT, 64, 0, stream>>>(hist, offsT, btot, B);
    prep_kernel<<<66, 256, 0, stream>>>(W1, W2, b2, lw, btot, w1t, w2l, c2, bbase, rowptr, N);
    partition_kernel<<<B, 256, 0, stream>>>(src, dst, bbase, offsT, epack, E, B);
    csr_build_kernel<<<NBKT, 512, 0, stream>>>(epack, bbase, x, rowptr, dis, xsp, csrc, N);

    aggx_kernel<<<(N + 255) / 256, 256, 0, stream>>>(xsp, dis, rowptr, csrc, a0p, N);
    mmfused_kernel<<<(N + 127) / 128, 256, 0, stream>>>(a0p, W0, b0, w1t, dis, t1f8, N);
    agg1_kernel<<<(N + 15) / 16, 256, 0, stream>>>(t1f8, dis, rowptr, csrc, b1, w2l, z, N);
    aggz_pool_kernel<<<(N + 255) / 256, 256, 0, stream>>>(z, dis, rowptr, csrc, bat, gsum, gcnt, N);

    final_kernel<<<1, 256, 0, stream>>>(gsum, gcnt, c2, lb, out);
}